// Round 5
// baseline (390.770 us; speedup 1.0000x reference)
//
#include <hip/hip_runtime.h>

typedef unsigned short u16;
typedef __bf16 bf8v __attribute__((ext_vector_type(8)));
typedef float f4v __attribute__((ext_vector_type(4)));

__device__ __forceinline__ float b2f(u16 v) {
  union { unsigned u; float f; } x; x.u = ((unsigned)v) << 16; return x.f;
}
__device__ __forceinline__ u16 f2b(float f) {
  union { float f; unsigned u; } x; x.f = f;
  unsigned r = (x.u + 0x7FFFu + ((x.u >> 16) & 1u)) >> 16;
  return (u16)r;
}

// ---------------------------------------------------------------------------
// Transpose + fp32->bf16 prep: dst[n][k] = bf16(src[k][n]); 256-row (K) slabs.
// ---------------------------------------------------------------------------
struct TrJobs {
  const float* src[20];
  u16* dst[20];
  int ncols[20];
  int tilebase[20];
  int njobs;
};

__global__ __launch_bounds__(256) void k_transpose(TrJobs jobs) {
  __shared__ float tl[32][33];
  const int tile = blockIdx.x;
  int j = 0;
  while (j + 1 < jobs.njobs && jobs.tilebase[j + 1] <= tile) j++;
  const int local = tile - jobs.tilebase[j];
  const int n = jobs.ncols[j];
  const int tilesPerRow = n >> 5;
  const int tr = local / tilesPerRow;
  const int tc = local % tilesPerRow;
  const float* s = jobs.src[j];
  u16* d = jobs.dst[j];
  const int tx = threadIdx.x & 31, ty = threadIdx.x >> 5;
#pragma unroll
  for (int r = 0; r < 4; r++) {
    const int row = tr * 32 + ty + r * 8;
    tl[ty + r * 8][tx] = s[(size_t)row * n + tc * 32 + tx];
  }
  __syncthreads();
#pragma unroll
  for (int r = 0; r < 4; r++) {
    const int drow = tc * 32 + ty + r * 8;
    d[(size_t)drow * 256 + tr * 32 + tx] = f2b(tl[tx][ty + r * 8]);
  }
}

// Concat biases (fp32) + convert S to bf16.
__global__ __launch_bounds__(256) void k_prep(
    const float* mbk, const float* mbv, const float* mbq, const float* S,
    float* bkv0, float* bqkv1, float* bqkv2, u16* Sb) {
  const int t = threadIdx.x;
  bkv0[t] = mbk[t]; bkv0[256 + t] = mbv[t];
  bqkv1[t] = mbq[256 + t]; bqkv1[256 + t] = mbk[256 + t]; bqkv1[512 + t] = mbv[256 + t];
  bqkv2[t] = mbq[512 + t]; bqkv2[256 + t] = mbk[512 + t]; bqkv2[512 + t] = mbv[512 + t];
  for (int r = 0; r < 16; r++) Sb[r * 256 + t] = f2b(S[r * 256 + t]);
}

// ---------------------------------------------------------------------------
// h = x.reshape(1024,48) @ gin_W + gin_b  -> bf16 (1024x256)
// ---------------------------------------------------------------------------
__global__ __launch_bounds__(256) void k_h(
    const float* __restrict__ x, const float* __restrict__ ginW,
    const float* __restrict__ ginb, u16* __restrict__ hb) {
  __shared__ float xs[4][48];
  const int t = threadIdx.x;
  const int row0 = blockIdx.x * 4;
  if (t < 192) {
    const int rr = t / 48, k = t % 48;
    xs[rr][k] = x[(size_t)(row0 + rr) * 48 + k];
  }
  __syncthreads();
  const float bias = ginb[t];
  float acc[4] = {bias, bias, bias, bias};
  for (int k = 0; k < 48; k++) {
    const float w = ginW[(size_t)k * 256 + t];
#pragma unroll
    for (int rr = 0; rr < 4; rr++) acc[rr] += xs[rr][k] * w;
  }
#pragma unroll
  for (int rr = 0; rr < 4; rr++) hb[(size_t)(row0 + rr) * 256 + t] = f2b(acc[rr]);
}

// ---------------------------------------------------------------------------
// Generic K=256 MFMA GEMM: out = [resid +] act(A @ Bt^T + bias)
// A: (M x 256) bf16; Bt: (N x 256) bf16 (pre-transposed); N multiple of 128.
// grid = (ceil(M/64), N/128), block 256. actmode: 0 none, 1 relu, 2 relu+resid
// ---------------------------------------------------------------------------
__global__ __launch_bounds__(256) void k_gemm(
    const u16* __restrict__ A, const u16* __restrict__ Bt,
    const float* __restrict__ bias, const float* __restrict__ resid,
    float* __restrict__ outF, u16* __restrict__ outB,
    int M, int N, int actmode) {
  __shared__ __align__(16) u16 As[64 * 40];
  __shared__ __align__(16) u16 Bs[128 * 40];
  const int t = threadIdx.x, lane = t & 63, wv = t >> 6;
  const int m0 = blockIdx.x * 64, n0 = blockIdx.y * 128;
  f4v acc[4][2];
#pragma unroll
  for (int mt = 0; mt < 4; mt++)
#pragma unroll
    for (int nt = 0; nt < 2; nt++) acc[mt][nt] = (f4v){0.f, 0.f, 0.f, 0.f};
  const int arow = t >> 2, akc = (t & 3) * 8;
  for (int kt = 0; kt < 8; kt++) {
    const int k0 = kt * 32;
    const int m = m0 + arow;
    uint4 a4 = (m < M) ? *(const uint4*)(A + (size_t)m * 256 + k0 + akc)
                       : make_uint4(0u, 0u, 0u, 0u);
    *(uint4*)(As + arow * 40 + akc) = a4;
#pragma unroll
    for (int rep = 0; rep < 2; rep++) {
      const int idx = rep * 256 + t;
      const int brow = idx >> 2, bkc = (idx & 3) * 8;
      uint4 b4 = *(const uint4*)(Bt + (size_t)(n0 + brow) * 256 + k0 + bkc);
      *(uint4*)(Bs + brow * 40 + bkc) = b4;
    }
    __syncthreads();
    bf8v af[4], bfg[2];
#pragma unroll
    for (int mt = 0; mt < 4; mt++)
      af[mt] = *(const bf8v*)(As + (mt * 16 + (lane & 15)) * 40 + (lane >> 4) * 8);
#pragma unroll
    for (int nt = 0; nt < 2; nt++)
      bfg[nt] = *(const bf8v*)(Bs + (wv * 32 + nt * 16 + (lane & 15)) * 40 + (lane >> 4) * 8);
#pragma unroll
    for (int mt = 0; mt < 4; mt++)
#pragma unroll
      for (int nt = 0; nt < 2; nt++)
        acc[mt][nt] = __builtin_amdgcn_mfma_f32_16x16x32_bf16(af[mt], bfg[nt], acc[mt][nt], 0, 0, 0);
    __syncthreads();
  }
#pragma unroll
  for (int mt = 0; mt < 4; mt++) {
    const int mb = m0 + mt * 16 + ((lane >> 4) << 2);
#pragma unroll
    for (int nt = 0; nt < 2; nt++) {
      const int n = n0 + wv * 32 + nt * 16 + (lane & 15);
      const float bv = bias ? bias[n] : 0.f;
#pragma unroll
      for (int r = 0; r < 4; r++) {
        const int m = mb + r;
        if (m < M) {
          float v = acc[mt][nt][r] + bv;
          if (actmode >= 1) v = fmaxf(v, 0.f);
          if (actmode == 2) v += resid[(size_t)m * N + n];
          if (outF) outF[(size_t)m * N + n] = v;
          if (outB) outB[(size_t)m * N + n] = f2b(v);
        }
      }
    }
  }
}

// ---------------------------------------------------------------------------
// Edge MLP + masked aggregation (the 17 GFLOP kernel).
// One WG per (b,i). agg[b,i,:] = sum_{j: adj!=0} relu(relu(hWi+hWj+geb1)@geW2+geb2)
// ---------------------------------------------------------------------------
__global__ __launch_bounds__(256, 2) void k_edge(
    const float* __restrict__ hWiWj, const float* __restrict__ adj,
    const float* __restrict__ geb1, const u16* __restrict__ W2t,
    const float* __restrict__ geb2, u16* __restrict__ aggB) {
  __shared__ __align__(16) u16 As[64 * 264];   // relu(pre) chunk, 64 rows x 256k (+8 pad)
  __shared__ __align__(16) u16 Bs[256 * 40];   // W2t k-tile, 256 n-rows x 32k (+8 pad)
  __shared__ float hi[256];
  __shared__ int jlist[256];
  __shared__ int cnt;
  const int t = threadIdx.x, lane = t & 63, wv = t >> 6;
  const int blk = blockIdx.x;
  const int b = blk >> 8, i = blk & 255;
  if (t == 0) cnt = 0;
  __syncthreads();
  {
    const float a = adj[(size_t)(b * 256 + i) * 256 + t];
    hi[t] = hWiWj[(size_t)(b * 256 + i) * 512 + t] + geb1[t];
    if (a != 0.f) { const int p = atomicAdd(&cnt, 1); jlist[p] = t; }
  }
  __syncthreads();
  const int nact = cnt;
  const int nch = (nact + 63) >> 6;
  float bias2[4];
#pragma unroll
  for (int nt = 0; nt < 4; nt++) bias2[nt] = geb2[wv * 64 + nt * 16 + (lane & 15)];
  float aggAcc[4] = {0.f, 0.f, 0.f, 0.f};

  for (int c = 0; c < nch; c++) {
    const int rows = min(64, nact - c * 64);
    {  // build A chunk: relu(hWi + hWj[j] + geb1) -> bf16
      const int r = t >> 2, q = t & 3;
      const bool valid = (r < rows);
      const int j = valid ? jlist[c * 64 + r] : jlist[0];
      const float4* s4 = (const float4*)(hWiWj + (size_t)(b * 256 + j) * 512 + 256 + q * 64);
      u16* dstrow = As + r * 264 + q * 64;
#pragma unroll
      for (int ii = 0; ii < 8; ii++) {
        const float4 v0 = s4[ii * 2];
        const float4 v1 = s4[ii * 2 + 1];
        const int k = q * 64 + ii * 8;
        union { u16 s[8]; uint4 qd; } pk;
        pk.s[0] = f2b(fmaxf(v0.x + hi[k + 0], 0.f));
        pk.s[1] = f2b(fmaxf(v0.y + hi[k + 1], 0.f));
        pk.s[2] = f2b(fmaxf(v0.z + hi[k + 2], 0.f));
        pk.s[3] = f2b(fmaxf(v0.w + hi[k + 3], 0.f));
        pk.s[4] = f2b(fmaxf(v1.x + hi[k + 4], 0.f));
        pk.s[5] = f2b(fmaxf(v1.y + hi[k + 5], 0.f));
        pk.s[6] = f2b(fmaxf(v1.z + hi[k + 6], 0.f));
        pk.s[7] = f2b(fmaxf(v1.w + hi[k + 7], 0.f));
        *(uint4*)(dstrow + ii * 8) = pk.qd;
      }
    }
    __syncthreads();
    f4v acc[4][4];
#pragma unroll
    for (int jt = 0; jt < 4; jt++)
#pragma unroll
      for (int nt = 0; nt < 4; nt++) acc[jt][nt] = (f4v){0.f, 0.f, 0.f, 0.f};
    for (int kt = 0; kt < 8; kt++) {
      {  // stage W2t k-tile (n-major)
        const u16* s = W2t + (size_t)t * 256 + kt * 32;
        u16* d = Bs + t * 40;
        *(uint4*)(d) = *(const uint4*)(s);
        *(uint4*)(d + 8) = *(const uint4*)(s + 8);
        *(uint4*)(d + 16) = *(const uint4*)(s + 16);
        *(uint4*)(d + 24) = *(const uint4*)(s + 24);
      }
      __syncthreads();
      bf8v af[4], bfg[4];
#pragma unroll
      for (int jt = 0; jt < 4; jt++)
        af[jt] = *(const bf8v*)(As + (jt * 16 + (lane & 15)) * 264 + kt * 32 + (lane >> 4) * 8);
#pragma unroll
      for (int nt = 0; nt < 4; nt++)
        bfg[nt] = *(const bf8v*)(Bs + (wv * 64 + nt * 16 + (lane & 15)) * 40 + (lane >> 4) * 8);
#pragma unroll
      for (int nt = 0; nt < 4; nt++)
#pragma unroll
        for (int jt = 0; jt < 4; jt++)
          acc[jt][nt] = __builtin_amdgcn_mfma_f32_16x16x32_bf16(af[jt], bfg[nt], acc[jt][nt], 0, 0, 0);
      __syncthreads();
    }
    const int rbase = (lane >> 4) * 4;
#pragma unroll
    for (int nt = 0; nt < 4; nt++) {
      float s = 0.f;
#pragma unroll
      for (int jt = 0; jt < 4; jt++) {
        const int r0 = jt * 16 + rbase;
#pragma unroll
        for (int r = 0; r < 4; r++) {
          const float e = fmaxf(acc[jt][nt][r] + bias2[nt], 0.f);
          s += (r0 + r < rows) ? e : 0.f;
        }
      }
      s += __shfl_xor(s, 16);
      s += __shfl_xor(s, 32);
      aggAcc[nt] += s;
    }
  }
  if (lane < 16) {
#pragma unroll
    for (int nt = 0; nt < 4; nt++) {
      const int n = wv * 64 + nt * 16 + lane;
      aggB[(size_t)(b * 256 + i) * 256 + n] = f2b(aggAcc[nt]);
    }
  }
}

// ---------------------------------------------------------------------------
// Attention core: O = q + softmax(q k^T / 16) v, per (b, head) WG.
// q rows shared across b when qshared=1 (mab1: Q = broadcast S).
// ---------------------------------------------------------------------------
__global__ __launch_bounds__(256) void k_attn(
    const u16* __restrict__ qbuf, int qstride, int qshared,
    const u16* __restrict__ kbuf, const u16* __restrict__ vbuf, int kvstride, int Lk,
    float* __restrict__ oF, u16* __restrict__ oB) {
  __shared__ float qs[16][32];
  __shared__ float sc[16][256];
  const int t = threadIdx.x, lane = t & 63, wv = t >> 6;
  const int b = blockIdx.x >> 3, hd = blockIdx.x & 7;
  for (int idx = t; idx < 512; idx += 256) {
    const int r = idx >> 5, d = idx & 31;
    const int qrow = qshared ? r : (b * 16 + r);
    qs[r][d] = b2f(qbuf[(size_t)qrow * qstride + hd * 32 + d]);
  }
  __syncthreads();
  if (t < Lk) {
    const int krow = b * Lk + t;
    float kv[32];
#pragma unroll
    for (int d = 0; d < 32; d++) kv[d] = b2f(kbuf[(size_t)krow * kvstride + hd * 32 + d]);
    for (int r = 0; r < 16; r++) {
      float s = 0.f;
#pragma unroll
      for (int d = 0; d < 32; d++) s += qs[r][d] * kv[d];
      sc[r][t] = s * 0.0625f;  // 1/sqrt(256)
    }
  }
  __syncthreads();
  for (int r = wv * 4; r < wv * 4 + 4; r++) {
    float v[4];
    float mx = -1e30f;
#pragma unroll
    for (int q2 = 0; q2 < 4; q2++) {
      const int j = lane + q2 * 64;
      v[q2] = (j < Lk) ? sc[r][j] : -1e30f;
      mx = fmaxf(mx, v[q2]);
    }
    for (int off = 32; off; off >>= 1) mx = fmaxf(mx, __shfl_xor(mx, off));
    float sum = 0.f;
#pragma unroll
    for (int q2 = 0; q2 < 4; q2++) {
      v[q2] = (lane + q2 * 64 < Lk) ? __expf(v[q2] - mx) : 0.f;
      sum += v[q2];
    }
    for (int off = 32; off; off >>= 1) sum += __shfl_xor(sum, off);
    const float inv = 1.f / sum;
#pragma unroll
    for (int q2 = 0; q2 < 4; q2++) {
      const int j = lane + q2 * 64;
      if (j < Lk) sc[r][j] = v[q2] * inv;
    }
  }
  __syncthreads();
  for (int idx = t; idx < 512; idx += 256) {
    const int r = idx >> 5, d = idx & 31;
    float acc = qs[r][d];
    for (int j = 0; j < Lk; j++)
      acc += sc[r][j] * b2f(vbuf[(size_t)(b * Lk + j) * kvstride + hd * 32 + d]);
    const int orow = b * 16 + r, col = hd * 32 + d;
    oF[(size_t)orow * 256 + col] = acc;
    oB[(size_t)orow * 256 + col] = f2b(acc);
  }
}

// ---------------------------------------------------------------------------
extern "C" void kernel_launch(void* const* d_in, const int* in_sizes, int n_in,
                              void* d_out, int out_size, void* d_ws, size_t ws_size,
                              hipStream_t stream) {
  const float* x    = (const float*)d_in[0];
  const float* adj  = (const float*)d_in[1];
  const float* ginW = (const float*)d_in[2];
  const float* ginb = (const float*)d_in[3];
  const float* geW1 = (const float*)d_in[4];
  const float* geb1 = (const float*)d_in[5];
  const float* geW2 = (const float*)d_in[6];
  const float* geb2 = (const float*)d_in[7];
  const float* gnW1 = (const float*)d_in[8];
  const float* gnb1 = (const float*)d_in[9];
  const float* gnW2 = (const float*)d_in[10];
  const float* gnb2 = (const float*)d_in[11];
  const float* goW  = (const float*)d_in[12];
  const float* gob  = (const float*)d_in[13];
  const float* S    = (const float*)d_in[14];
  const float* mWq  = (const float*)d_in[15];
  const float* mbq  = (const float*)d_in[16];
  const float* mWk  = (const float*)d_in[17];
  const float* mbk  = (const float*)d_in[18];
  const float* mWv  = (const float*)d_in[19];
  const float* mbv  = (const float*)d_in[20];
  const float* mWo  = (const float*)d_in[21];
  const float* mbo  = (const float*)d_in[22];
  const float* finW = (const float*)d_in[23];
  const float* finb = (const float*)d_in[24];

  char* wp = (char*)d_ws;
  size_t off = 0;
  auto alloc = [&](size_t bytes) -> char* {
    char* p = wp + off;
    off += (bytes + 255) & ~(size_t)255;
    return p;
  };
  u16* h_bf     = (u16*)alloc(1024 * 256 * 2);
  float* hWiWjf = (float*)alloc((size_t)1024 * 512 * 4);
  u16* BtWiWj   = (u16*)alloc(512 * 256 * 2);
  u16* W2t      = (u16*)alloc(256 * 256 * 2);
  u16* Btgn1    = (u16*)alloc(256 * 256 * 2);
  u16* Btgn2    = (u16*)alloc(256 * 256 * 2);
  u16* Btgo     = (u16*)alloc(256 * 256 * 2);
  u16* Btq0     = (u16*)alloc(256 * 256 * 2);
  u16* Btkv0    = (u16*)alloc(512 * 256 * 2);
  u16* Btqkv1   = (u16*)alloc(768 * 256 * 2);
  u16* Btqkv2   = (u16*)alloc(768 * 256 * 2);
  u16* Bto0     = (u16*)alloc(256 * 256 * 2);
  u16* Bto1     = (u16*)alloc(256 * 256 * 2);
  u16* Bto2     = (u16*)alloc(256 * 256 * 2);
  u16* Btfin    = (u16*)alloc(384 * 256 * 2);
  float* bkv0   = (float*)alloc(512 * 4);
  float* bqkv1  = (float*)alloc(768 * 4);
  float* bqkv2  = (float*)alloc(768 * 4);
  u16* Sb       = (u16*)alloc(16 * 256 * 2);
  u16* q1b      = (u16*)alloc(16 * 256 * 2);
  u16* agg_b    = (u16*)alloc(1024 * 256 * 2);
  u16* n1b      = (u16*)alloc(1024 * 256 * 2);
  u16* n2b      = (u16*)alloc(1024 * 256 * 2);
  u16* encb     = (u16*)alloc(1024 * 256 * 2);
  u16* kv1      = (u16*)alloc(1024 * 512 * 2);
  float* o1f    = (float*)alloc(64 * 256 * 4);
  u16* o1b      = (u16*)alloc(64 * 256 * 2);
  float* o1pf   = (float*)alloc(64 * 256 * 4);
  u16* o1pb     = (u16*)alloc(64 * 256 * 2);
  u16* qkv2     = (u16*)alloc(64 * 768 * 2);
  float* o2f    = (float*)alloc(64 * 256 * 4);
  u16* o2b      = (u16*)alloc(64 * 256 * 2);
  float* o2pf   = (float*)alloc(64 * 256 * 4);
  u16* o2pb     = (u16*)alloc(64 * 256 * 2);
  u16* qkv3     = (u16*)alloc(64 * 768 * 2);
  float* o3f    = (float*)alloc(64 * 256 * 4);
  u16* o3b      = (u16*)alloc(64 * 256 * 2);
  float* o3pf   = (float*)alloc(64 * 256 * 4);
  u16* o3pb     = (u16*)alloc(64 * 256 * 2);
  (void)ws_size; (void)in_sizes; (void)n_in; (void)out_size;

  TrJobs J{};
  int nj = 0, tiles = 0;
  auto addJ = [&](const float* s, u16* d, int ncols) {
    J.src[nj] = s; J.dst[nj] = d; J.ncols[nj] = ncols; J.tilebase[nj] = tiles;
    tiles += 8 * (ncols / 32); nj++;
  };
  addJ(geW1, BtWiWj, 256);
  addJ(geW1 + 65536, BtWiWj + 65536, 256);
  addJ(geW2, W2t, 256);
  addJ(gnW1, Btgn1, 256);
  addJ(gnW2, Btgn2, 256);
  addJ(goW, Btgo, 256);
  addJ(mWq, Btq0, 256);
  addJ(mWk, Btkv0, 256);
  addJ(mWv, Btkv0 + 65536, 256);
  addJ(mWq + 65536, Btqkv1, 256);
  addJ(mWk + 65536, Btqkv1 + 65536, 256);
  addJ(mWv + 65536, Btqkv1 + 131072, 256);
  addJ(mWq + 131072, Btqkv2, 256);
  addJ(mWk + 131072, Btqkv2 + 65536, 256);
  addJ(mWv + 131072, Btqkv2 + 131072, 256);
  addJ(mWo, Bto0, 256);
  addJ(mWo + 65536, Bto1, 256);
  addJ(mWo + 131072, Bto2, 256);
  addJ(finW, Btfin, 384);
  J.njobs = nj;

  k_transpose<<<dim3(tiles), dim3(256), 0, stream>>>(J);
  k_prep<<<dim3(1), dim3(256), 0, stream>>>(mbk, mbv, mbq, S, bkv0, bqkv1, bqkv2, Sb);
  k_h<<<dim3(256), dim3(256), 0, stream>>>(x, ginW, ginb, h_bf);
  // q1 = S @ Wq0 + bq0 (shared across batch)
  k_gemm<<<dim3(1, 2), dim3(256), 0, stream>>>(Sb, Btq0, mbq, nullptr, nullptr, q1b, 16, 256, 0);
  // [hWi | hWj] = h @ [Wi Wj]  (no bias; geb1 folded into edge kernel)
  k_gemm<<<dim3(16, 4), dim3(256), 0, stream>>>(h_bf, BtWiWj, nullptr, nullptr, hWiWjf, nullptr, 1024, 512, 0);
  // edge MLP + masked aggregation
  k_edge<<<dim3(1024), dim3(256), 0, stream>>>(hWiWjf, adj, geb1, W2t, geb2, agg_b);
  // node MLP + encoder proj
  k_gemm<<<dim3(16, 2), dim3(256), 0, stream>>>(agg_b, Btgn1, gnb1, nullptr, nullptr, n1b, 1024, 256, 1);
  k_gemm<<<dim3(16, 2), dim3(256), 0, stream>>>(n1b, Btgn2, gnb2, nullptr, nullptr, n2b, 1024, 256, 1);
  k_gemm<<<dim3(16, 2), dim3(256), 0, stream>>>(n2b, Btgo, gob, nullptr, nullptr, encb, 1024, 256, 0);
  // mab1 K/V projections
  k_gemm<<<dim3(16, 4), dim3(256), 0, stream>>>(encb, Btkv0, bkv0, nullptr, nullptr, kv1, 1024, 512, 0);
  // mab1 attention (Lk=256), o-proj
  k_attn<<<dim3(32), dim3(256), 0, stream>>>(q1b, 256, 1, kv1, kv1 + 256, 512, 256, o1f, o1b);
  k_gemm<<<dim3(1, 2), dim3(256), 0, stream>>>(o1b, Bto0, mbo, o1f, o1pf, o1pb, 64, 256, 2);
  // mab2
  k_gemm<<<dim3(1, 6), dim3(256), 0, stream>>>(o1pb, Btqkv1, bqkv1, nullptr, nullptr, qkv2, 64, 768, 0);
  k_attn<<<dim3(32), dim3(256), 0, stream>>>(qkv2, 768, 0, qkv2 + 256, qkv2 + 512, 768, 16, o2f, o2b);
  k_gemm<<<dim3(1, 2), dim3(256), 0, stream>>>(o2b, Bto1, mbo + 256, o2f, o2pf, o2pb, 64, 256, 2);
  // mab3
  k_gemm<<<dim3(1, 6), dim3(256), 0, stream>>>(o2pb, Btqkv2, bqkv2, nullptr, nullptr, qkv3, 64, 768, 0);
  k_attn<<<dim3(32), dim3(256), 0, stream>>>(qkv3, 768, 0, qkv3 + 256, qkv3 + 512, 768, 16, o3f, o3b);
  k_gemm<<<dim3(1, 2), dim3(256), 0, stream>>>(o3b, Bto2, mbo + 512, o3f, o3pf, o3pb, 64, 256, 2);
  // final projection -> d_out (FP32! reference output dtype is float32)
  k_gemm<<<dim3(1, 3), dim3(256), 0, stream>>>(o3pb, Btfin, finb, nullptr, (float*)d_out, nullptr, 64, 384, 0);
}

// Round 6
// 389.464 us; speedup vs baseline: 1.0034x; 1.0034x over previous
//
#include <hip/hip_runtime.h>

typedef unsigned short u16;
typedef __bf16 bf8v __attribute__((ext_vector_type(8)));
typedef float f4v __attribute__((ext_vector_type(4)));

__device__ __forceinline__ float b2f(u16 v) {
  union { unsigned u; float f; } x; x.u = ((unsigned)v) << 16; return x.f;
}
__device__ __forceinline__ u16 f2b(float f) {
  union { float f; unsigned u; } x; x.f = f;
  unsigned r = (x.u + 0x7FFFu + ((x.u >> 16) & 1u)) >> 16;
  return (u16)r;
}

// ---------------------------------------------------------------------------
// Fused prologue: weight transposes (fp32->bf16), bias concat, h-proj, q1-proj
// ---------------------------------------------------------------------------
struct TrJobs {
  const float* src[20];
  u16* dst[20];
  int ncols[20];
  int tilebase[20];
  int njobs;
};

struct PreArgs {
  TrJobs J;
  int trTiles, hBase, prepBid, q1Bid;
  const float *x, *ginW, *ginb;
  u16* h_bf;
  const float *mbk, *mbv, *mbq, *S, *mWq;
  float *bkv0, *bqkv1, *bqkv2;
  u16* q1b;
};

__global__ __launch_bounds__(256) void k_pre(PreArgs a) {
  __shared__ float tl[32][33];
  __shared__ float xs[4][48];
  __shared__ float Ss[4096];
  const int bid = blockIdx.x;
  const int t = threadIdx.x;

  if (bid < a.trTiles) {  // ---- transpose tile ----
    int j = 0;
    while (j + 1 < a.J.njobs && a.J.tilebase[j + 1] <= bid) j++;
    const int local = bid - a.J.tilebase[j];
    const int n = a.J.ncols[j];
    const int tilesPerRow = n >> 5;
    const int tr = local / tilesPerRow;
    const int tc = local % tilesPerRow;
    const float* s = a.J.src[j];
    u16* d = a.J.dst[j];
    const int tx = t & 31, ty = t >> 5;
#pragma unroll
    for (int r = 0; r < 4; r++) {
      const int row = tr * 32 + ty + r * 8;
      tl[ty + r * 8][tx] = s[(size_t)row * n + tc * 32 + tx];
    }
    __syncthreads();
#pragma unroll
    for (int r = 0; r < 4; r++) {
      const int drow = tc * 32 + ty + r * 8;
      d[(size_t)drow * 256 + tr * 32 + tx] = f2b(tl[tx][ty + r * 8]);
    }
    return;
  }
  if (bid < a.hBase + 256 && bid >= a.hBase) {  // ---- h projection ----
    const int row0 = (bid - a.hBase) * 4;
    if (t < 192) {
      const int rr = t / 48, k = t % 48;
      xs[rr][k] = a.x[(size_t)(row0 + rr) * 48 + k];
    }
    __syncthreads();
    const float bias = a.ginb[t];
    float acc[4] = {bias, bias, bias, bias};
    for (int k = 0; k < 48; k++) {
      const float w = a.ginW[(size_t)k * 256 + t];
#pragma unroll
      for (int rr = 0; rr < 4; rr++) acc[rr] += xs[rr][k] * w;
    }
#pragma unroll
    for (int rr = 0; rr < 4; rr++) a.h_bf[(size_t)(row0 + rr) * 256 + t] = f2b(acc[rr]);
    return;
  }
  if (bid == a.prepBid) {  // ---- bias concat ----
    a.bkv0[t] = a.mbk[t]; a.bkv0[256 + t] = a.mbv[t];
    a.bqkv1[t] = a.mbq[256 + t]; a.bqkv1[256 + t] = a.mbk[256 + t]; a.bqkv1[512 + t] = a.mbv[256 + t];
    a.bqkv2[t] = a.mbq[512 + t]; a.bqkv2[256 + t] = a.mbk[512 + t]; a.bqkv2[512 + t] = a.mbv[512 + t];
    return;
  }
  if (bid == a.q1Bid) {  // ---- q1 = S @ Wq0 + bq0 (fp32 vector, one block) ----
    for (int idx = t; idx < 4096; idx += 256) Ss[idx] = a.S[idx];
    __syncthreads();
    float acc[16];
#pragma unroll
    for (int r = 0; r < 16; r++) acc[r] = 0.f;
    for (int k = 0; k < 256; k++) {
      const float w = a.mWq[(size_t)k * 256 + t];
#pragma unroll
      for (int r = 0; r < 16; r++) acc[r] += Ss[r * 256 + k] * w;
    }
    const float bq = a.mbq[t];
#pragma unroll
    for (int r = 0; r < 16; r++) a.q1b[r * 256 + t] = f2b(acc[r] + bq);
    return;
  }
}

// ---------------------------------------------------------------------------
// Standalone MFMA GEMM (used once for hWiWj). Same as verified round-5 kernel.
// ---------------------------------------------------------------------------
__global__ __launch_bounds__(256) void k_gemm(
    const u16* __restrict__ A, const u16* __restrict__ Bt,
    const float* __restrict__ bias, const float* __restrict__ resid,
    float* __restrict__ outF, u16* __restrict__ outB,
    int M, int N, int actmode) {
  __shared__ __align__(16) u16 As[64 * 40];
  __shared__ __align__(16) u16 Bs[128 * 40];
  const int t = threadIdx.x, lane = t & 63, wv = t >> 6;
  const int m0 = blockIdx.x * 64, n0 = blockIdx.y * 128;
  f4v acc[4][2];
#pragma unroll
  for (int mt = 0; mt < 4; mt++)
#pragma unroll
    for (int nt = 0; nt < 2; nt++) acc[mt][nt] = (f4v){0.f, 0.f, 0.f, 0.f};
  const int arow = t >> 2, akc = (t & 3) * 8;
  for (int kt = 0; kt < 8; kt++) {
    const int k0 = kt * 32;
    const int m = m0 + arow;
    uint4 a4 = (m < M) ? *(const uint4*)(A + (size_t)m * 256 + k0 + akc)
                       : make_uint4(0u, 0u, 0u, 0u);
    *(uint4*)(As + arow * 40 + akc) = a4;
#pragma unroll
    for (int rep = 0; rep < 2; rep++) {
      const int idx = rep * 256 + t;
      const int brow = idx >> 2, bkc = (idx & 3) * 8;
      uint4 b4 = *(const uint4*)(Bt + (size_t)(n0 + brow) * 256 + k0 + bkc);
      *(uint4*)(Bs + brow * 40 + bkc) = b4;
    }
    __syncthreads();
    bf8v af[4], bfg[2];
#pragma unroll
    for (int mt = 0; mt < 4; mt++)
      af[mt] = *(const bf8v*)(As + (mt * 16 + (lane & 15)) * 40 + (lane >> 4) * 8);
#pragma unroll
    for (int nt = 0; nt < 2; nt++)
      bfg[nt] = *(const bf8v*)(Bs + (wv * 32 + nt * 16 + (lane & 15)) * 40 + (lane >> 4) * 8);
#pragma unroll
    for (int mt = 0; mt < 4; mt++)
#pragma unroll
      for (int nt = 0; nt < 2; nt++)
        acc[mt][nt] = __builtin_amdgcn_mfma_f32_16x16x32_bf16(af[mt], bfg[nt], acc[mt][nt], 0, 0, 0);
    __syncthreads();
  }
#pragma unroll
  for (int mt = 0; mt < 4; mt++) {
    const int mb = m0 + mt * 16 + ((lane >> 4) << 2);
#pragma unroll
    for (int nt = 0; nt < 2; nt++) {
      const int n = n0 + wv * 32 + nt * 16 + (lane & 15);
      const float bv = bias ? bias[n] : 0.f;
#pragma unroll
      for (int r = 0; r < 4; r++) {
        const int m = mb + r;
        if (m < M) {
          float v = acc[mt][nt][r] + bv;
          if (actmode >= 1) v = fmaxf(v, 0.f);
          if (actmode == 2) v += resid[(size_t)m * N + n];
          if (outF) outF[(size_t)m * N + n] = v;
          if (outB) outB[(size_t)m * N + n] = f2b(v);
        }
      }
    }
  }
}

// ---------------------------------------------------------------------------
// Edge MLP + masked aggregation v2: B-fragments in registers (no Bs staging,
// no barriers in the kt loop). W2t is L2-resident (128 KB, shared by all WGs).
// ---------------------------------------------------------------------------
__global__ __launch_bounds__(256, 2) void k_edge(
    const float* __restrict__ hWiWj, const float* __restrict__ adj,
    const float* __restrict__ geb1, const u16* __restrict__ W2t,
    const float* __restrict__ geb2, u16* __restrict__ aggB) {
  __shared__ __align__(16) u16 As[64 * 264];   // relu(pre) chunk
  __shared__ float hi[256];
  __shared__ int jlist[256];
  __shared__ int cnt;
  const int t = threadIdx.x, lane = t & 63, wv = t >> 6;
  const int b = blockIdx.x >> 8, i = blockIdx.x & 255;
  if (t == 0) cnt = 0;
  __syncthreads();
  {
    const float a = adj[(size_t)(b * 256 + i) * 256 + t];
    hi[t] = hWiWj[(size_t)(b * 256 + i) * 512 + t] + geb1[t];
    if (a != 0.f) { const int p = atomicAdd(&cnt, 1); jlist[p] = t; }
  }
  __syncthreads();
  const int nact = cnt;
  if (nact == 0) {
    if (lane < 16 && wv < 4) {
#pragma unroll
      for (int nt = 0; nt < 4; nt++)
        aggB[(size_t)(b * 256 + i) * 256 + wv * 64 + nt * 16 + lane] = 0;
    }
    return;
  }
  const int nch = (nact + 63) >> 6;
  float bias2[4];
#pragma unroll
  for (int nt = 0; nt < 4; nt++) bias2[nt] = geb2[wv * 64 + nt * 16 + (lane & 15)];
  float aggAcc[4] = {0.f, 0.f, 0.f, 0.f};
  const u16* wb = W2t + ((size_t)(wv * 64 + (lane & 15)) << 8) + ((lane >> 4) << 3);

  for (int c = 0; c < nch; c++) {
    const int rows = min(64, nact - c * 64);
    {  // build A chunk: relu(hWi + hWj[j] + geb1) -> bf16
      const int r = t >> 2, q = t & 3;
      const bool valid = (r < rows);
      const int j = valid ? jlist[c * 64 + r] : jlist[0];
      const float4* s4 = (const float4*)(hWiWj + (size_t)(b * 256 + j) * 512 + 256 + q * 64);
      u16* dstrow = As + r * 264 + q * 64;
#pragma unroll
      for (int ii = 0; ii < 8; ii++) {
        const float4 v0 = s4[ii * 2];
        const float4 v1 = s4[ii * 2 + 1];
        const int k = q * 64 + ii * 8;
        union { u16 s[8]; uint4 qd; } pk;
        pk.s[0] = f2b(fmaxf(v0.x + hi[k + 0], 0.f));
        pk.s[1] = f2b(fmaxf(v0.y + hi[k + 1], 0.f));
        pk.s[2] = f2b(fmaxf(v0.z + hi[k + 2], 0.f));
        pk.s[3] = f2b(fmaxf(v0.w + hi[k + 3], 0.f));
        pk.s[4] = f2b(fmaxf(v1.x + hi[k + 4], 0.f));
        pk.s[5] = f2b(fmaxf(v1.y + hi[k + 5], 0.f));
        pk.s[6] = f2b(fmaxf(v1.z + hi[k + 6], 0.f));
        pk.s[7] = f2b(fmaxf(v1.w + hi[k + 7], 0.f));
        *(uint4*)(dstrow + ii * 8) = pk.qd;
      }
    }
    __syncthreads();
    f4v acc[4][4];
#pragma unroll
    for (int jt = 0; jt < 4; jt++)
#pragma unroll
      for (int nt = 0; nt < 4; nt++) acc[jt][nt] = (f4v){0.f, 0.f, 0.f, 0.f};
    bf8v bcur[4];
#pragma unroll
    for (int nt = 0; nt < 4; nt++) bcur[nt] = *(const bf8v*)(wb + nt * 4096);
#pragma unroll
    for (int kt = 0; kt < 8; kt++) {
      bf8v bnxt[4];
      if (kt < 7) {
#pragma unroll
        for (int nt = 0; nt < 4; nt++)
          bnxt[nt] = *(const bf8v*)(wb + nt * 4096 + (kt + 1) * 32);
      }
      bf8v af[4];
#pragma unroll
      for (int jt = 0; jt < 4; jt++)
        af[jt] = *(const bf8v*)(As + (jt * 16 + (lane & 15)) * 264 + kt * 32 + (lane >> 4) * 8);
#pragma unroll
      for (int nt = 0; nt < 4; nt++)
#pragma unroll
        for (int jt = 0; jt < 4; jt++)
          acc[jt][nt] = __builtin_amdgcn_mfma_f32_16x16x32_bf16(af[jt], bcur[nt], acc[jt][nt], 0, 0, 0);
      if (kt < 7) {
#pragma unroll
        for (int nt = 0; nt < 4; nt++) bcur[nt] = bnxt[nt];
      }
    }
    const int rbase = (lane >> 4) * 4;
#pragma unroll
    for (int nt = 0; nt < 4; nt++) {
      float s = 0.f;
#pragma unroll
      for (int jt = 0; jt < 4; jt++) {
        const int r0 = jt * 16 + rbase;
#pragma unroll
        for (int r = 0; r < 4; r++) {
          const float e = fmaxf(acc[jt][nt][r] + bias2[nt], 0.f);
          s += (r0 + r < rows) ? e : 0.f;
        }
      }
      s += __shfl_xor(s, 16);
      s += __shfl_xor(s, 32);
      aggAcc[nt] += s;
    }
    __syncthreads();
  }
  if (lane < 16) {
#pragma unroll
    for (int nt = 0; nt < 4; nt++) {
      const int n = wv * 64 + nt * 16 + lane;
      aggB[(size_t)(b * 256 + i) * 256 + n] = f2b(aggAcc[nt]);
    }
  }
}

// ---------------------------------------------------------------------------
// Fused tail: node MLP -> enc -> kv1 -> attn1 -> oproj1 -> mab2 -> mab3 -> fin
// 64 persistent blocks; manual device-scope grid barrier (all co-resident).
// ---------------------------------------------------------------------------
#define NBLK 64

__device__ __forceinline__ void gridbar(int* cnt, int gen) {
  __syncthreads();
  if (threadIdx.x == 0) {
    __threadfence();
    atomicAdd(cnt, 1);
    while (atomicAdd(cnt, 0) < NBLK * gen) __builtin_amdgcn_s_sleep(2);
    __threadfence();
  }
  __syncthreads();
}

__device__ void gemm_tile(const u16* __restrict__ A, const u16* __restrict__ Bt,
                          const float* __restrict__ bias, const float* __restrict__ resid,
                          float* __restrict__ outF, u16* __restrict__ outB,
                          int M, int N, int m0, int n0, int actmode,
                          u16* As, u16* Bs, int t) {
  const int lane = t & 63, wv = t >> 6;
  f4v acc[4][2];
#pragma unroll
  for (int mt = 0; mt < 4; mt++)
#pragma unroll
    for (int nt = 0; nt < 2; nt++) acc[mt][nt] = (f4v){0.f, 0.f, 0.f, 0.f};
  const int arow = t >> 2, akc = (t & 3) * 8;
  for (int kt = 0; kt < 8; kt++) {
    const int k0 = kt * 32;
    const int m = m0 + arow;
    uint4 a4 = (m < M) ? *(const uint4*)(A + (size_t)m * 256 + k0 + akc)
                       : make_uint4(0u, 0u, 0u, 0u);
    *(uint4*)(As + arow * 40 + akc) = a4;
#pragma unroll
    for (int rep = 0; rep < 2; rep++) {
      const int idx = rep * 256 + t;
      const int brow = idx >> 2, bkc = (idx & 3) * 8;
      uint4 b4 = *(const uint4*)(Bt + (size_t)(n0 + brow) * 256 + k0 + bkc);
      *(uint4*)(Bs + brow * 40 + bkc) = b4;
    }
    __syncthreads();
    bf8v af[4], bfg[2];
#pragma unroll
    for (int mt = 0; mt < 4; mt++)
      af[mt] = *(const bf8v*)(As + (mt * 16 + (lane & 15)) * 40 + (lane >> 4) * 8);
#pragma unroll
    for (int nt = 0; nt < 2; nt++)
      bfg[nt] = *(const bf8v*)(Bs + (wv * 32 + nt * 16 + (lane & 15)) * 40 + (lane >> 4) * 8);
#pragma unroll
    for (int mt = 0; mt < 4; mt++)
#pragma unroll
      for (int nt = 0; nt < 2; nt++)
        acc[mt][nt] = __builtin_amdgcn_mfma_f32_16x16x32_bf16(af[mt], bfg[nt], acc[mt][nt], 0, 0, 0);
    __syncthreads();
  }
#pragma unroll
  for (int mt = 0; mt < 4; mt++) {
    const int mb = m0 + mt * 16 + ((lane >> 4) << 2);
#pragma unroll
    for (int nt = 0; nt < 2; nt++) {
      const int n = n0 + wv * 32 + nt * 16 + (lane & 15);
      const float bv = bias ? bias[n] : 0.f;
#pragma unroll
      for (int r = 0; r < 4; r++) {
        const int m = mb + r;
        if (m < M) {
          float v = acc[mt][nt][r] + bv;
          if (actmode >= 1) v = fmaxf(v, 0.f);
          if (actmode == 2) v += resid[(size_t)m * N + n];
          if (outF) outF[(size_t)m * N + n] = v;
          if (outB) outB[(size_t)m * N + n] = f2b(v);
        }
      }
    }
  }
}

__device__ void attn_tile(const u16* __restrict__ qbuf, int qstride, int qshared,
                          const u16* __restrict__ kbuf, const u16* __restrict__ vbuf,
                          int kvstride, int Lk,
                          float* __restrict__ oF, u16* __restrict__ oB,
                          int b, int hd, float* qs, float* sc, float* vs, int t) {
  const int lane = t & 63, wv = t >> 6;
  for (int idx = t; idx < 512; idx += 256) {
    const int r = idx >> 5, d = idx & 31;
    const int qrow = qshared ? r : (b * 16 + r);
    qs[r * 32 + d] = b2f(qbuf[(size_t)qrow * qstride + hd * 32 + d]);
  }
  __syncthreads();
  if (t < Lk) {
    float kv[32];
#pragma unroll
    for (int d = 0; d < 32; d++) kv[d] = b2f(kbuf[(size_t)(b * Lk + t) * kvstride + hd * 32 + d]);
    for (int r = 0; r < 16; r++) {
      float s = 0.f;
#pragma unroll
      for (int d = 0; d < 32; d++) s += qs[r * 32 + d] * kv[d];
      sc[r * 256 + t] = s * 0.0625f;  // 1/sqrt(256)
    }
  }
  __syncthreads();
  for (int r = wv * 4; r < wv * 4 + 4; r++) {
    float v[4];
    float mx = -1e30f;
#pragma unroll
    for (int q2 = 0; q2 < 4; q2++) {
      const int j = lane + q2 * 64;
      v[q2] = (j < Lk) ? sc[r * 256 + j] : -1e30f;
      mx = fmaxf(mx, v[q2]);
    }
    for (int off = 32; off; off >>= 1) mx = fmaxf(mx, __shfl_xor(mx, off));
    float sum = 0.f;
#pragma unroll
    for (int q2 = 0; q2 < 4; q2++) {
      v[q2] = (lane + q2 * 64 < Lk) ? __expf(v[q2] - mx) : 0.f;
      sum += v[q2];
    }
    for (int off = 32; off; off >>= 1) sum += __shfl_xor(sum, off);
    const float inv = 1.f / sum;
#pragma unroll
    for (int q2 = 0; q2 < 4; q2++) {
      const int j = lane + q2 * 64;
      if (j < Lk) sc[r * 256 + j] = v[q2] * inv;
    }
  }
  __syncthreads();
  for (int idx = t; idx < Lk * 32; idx += 256)
    vs[idx] = b2f(vbuf[(size_t)(b * Lk + (idx >> 5)) * kvstride + hd * 32 + (idx & 31)]);
  __syncthreads();
  const int r0 = t >> 5, d = t & 31;
  float a0 = qs[r0 * 32 + d], a1 = qs[(r0 + 8) * 32 + d];
  for (int j = 0; j < Lk; j++) {
    const float vv = vs[j * 32 + d];
    a0 += sc[r0 * 256 + j] * vv;
    a1 += sc[(r0 + 8) * 256 + j] * vv;
  }
  const int c0 = hd * 32 + d;
  oF[(size_t)(b * 16 + r0) * 256 + c0] = a0;
  oB[(size_t)(b * 16 + r0) * 256 + c0] = f2b(a0);
  oF[(size_t)(b * 16 + r0 + 8) * 256 + c0] = a1;
  oB[(size_t)(b * 16 + r0 + 8) * 256 + c0] = f2b(a1);
}

struct TailArgs {
  const u16 *agg, *Btgn1, *Btgn2, *Btgo, *Btkv0, *Btqkv1, *Btqkv2;
  const u16 *Bto0, *Bto1, *Bto2, *Btfin, *q1b;
  const float *gnb1, *gnb2, *gob, *bkv0, *bqkv1, *bqkv2, *mbo, *finb;
  u16 *n1b, *n2b, *encb, *kv1, *o1b, *o1pb, *qkv2b, *o2b, *o2pb, *qkv3b, *o3b, *o3pb;
  float *o1f, *o2f, *o3f, *outF;
  int* bar;
};

__global__ __launch_bounds__(256) void k_tail(TailArgs a) {
  __shared__ __align__(16) char smem[51200];
  const int bid = blockIdx.x;
  const int t = threadIdx.x;
  u16* As = (u16*)smem;
  u16* Bs = (u16*)(smem + 5120);
  float* qs = (float*)smem;
  float* sc = (float*)(smem + 2048);
  float* vs = (float*)(smem + 2048 + 16384);

  // node MLP
  if (bid < 32) gemm_tile(a.agg, a.Btgn1, a.gnb1, nullptr, nullptr, a.n1b, 1024, 256, (bid >> 1) * 64, (bid & 1) * 128, 1, As, Bs, t);
  gridbar(a.bar, 1);
  if (bid < 32) gemm_tile(a.n1b, a.Btgn2, a.gnb2, nullptr, nullptr, a.n2b, 1024, 256, (bid >> 1) * 64, (bid & 1) * 128, 1, As, Bs, t);
  gridbar(a.bar, 2);
  if (bid < 32) gemm_tile(a.n2b, a.Btgo, a.gob, nullptr, nullptr, a.encb, 1024, 256, (bid >> 1) * 64, (bid & 1) * 128, 0, As, Bs, t);
  gridbar(a.bar, 3);
  // kv1
  gemm_tile(a.encb, a.Btkv0, a.bkv0, nullptr, nullptr, a.kv1, 1024, 512, (bid >> 2) * 64, (bid & 3) * 128, 0, As, Bs, t);
  gridbar(a.bar, 4);
  // mab1
  if (bid < 32) attn_tile(a.q1b, 256, 1, a.kv1, a.kv1 + 256, 512, 256, a.o1f, a.o1b, bid >> 3, bid & 7, qs, sc, vs, t);
  gridbar(a.bar, 5);
  if (bid < 2) gemm_tile(a.o1b, a.Bto0, a.mbo, a.o1f, nullptr, a.o1pb, 64, 256, 0, bid * 128, 2, As, Bs, t);
  gridbar(a.bar, 6);
  // mab2
  if (bid < 6) gemm_tile(a.o1pb, a.Btqkv1, a.bqkv1, nullptr, nullptr, a.qkv2b, 64, 768, 0, bid * 128, 0, As, Bs, t);
  gridbar(a.bar, 7);
  if (bid < 32) attn_tile(a.qkv2b, 768, 0, a.qkv2b + 256, a.qkv2b + 512, 768, 16, a.o2f, a.o2b, bid >> 3, bid & 7, qs, sc, vs, t);
  gridbar(a.bar, 8);
  if (bid < 2) gemm_tile(a.o2b, a.Bto1, a.mbo + 256, a.o2f, nullptr, a.o2pb, 64, 256, 0, bid * 128, 2, As, Bs, t);
  gridbar(a.bar, 9);
  // mab3
  if (bid < 6) gemm_tile(a.o2pb, a.Btqkv2, a.bqkv2, nullptr, nullptr, a.qkv3b, 64, 768, 0, bid * 128, 0, As, Bs, t);
  gridbar(a.bar, 10);
  if (bid < 32) attn_tile(a.qkv3b, 768, 0, a.qkv3b + 256, a.qkv3b + 512, 768, 16, a.o3f, a.o3b, bid >> 3, bid & 7, qs, sc, vs, t);
  gridbar(a.bar, 11);
  if (bid < 2) gemm_tile(a.o3b, a.Bto2, a.mbo + 512, a.o3f, nullptr, a.o3pb, 64, 256, 0, bid * 128, 2, As, Bs, t);
  gridbar(a.bar, 12);
  // final projection -> d_out fp32
  if (bid < 3) gemm_tile(a.o3pb, a.Btfin, a.finb, nullptr, a.outF, nullptr, 64, 384, 0, bid * 128, 0, As, Bs, t);
}

// ---------------------------------------------------------------------------
extern "C" void kernel_launch(void* const* d_in, const int* in_sizes, int n_in,
                              void* d_out, int out_size, void* d_ws, size_t ws_size,
                              hipStream_t stream) {
  const float* x    = (const float*)d_in[0];
  const float* adj  = (const float*)d_in[1];
  const float* ginW = (const float*)d_in[2];
  const float* ginb = (const float*)d_in[3];
  const float* geW1 = (const float*)d_in[4];
  const float* geb1 = (const float*)d_in[5];
  const float* geW2 = (const float*)d_in[6];
  const float* geb2 = (const float*)d_in[7];
  const float* gnW1 = (const float*)d_in[8];
  const float* gnb1 = (const float*)d_in[9];
  const float* gnW2 = (const float*)d_in[10];
  const float* gnb2 = (const float*)d_in[11];
  const float* goW  = (const float*)d_in[12];
  const float* gob  = (const float*)d_in[13];
  const float* S    = (const float*)d_in[14];
  const float* mWq  = (const float*)d_in[15];
  const float* mbq  = (const float*)d_in[16];
  const float* mWk  = (const float*)d_in[17];
  const float* mbk  = (const float*)d_in[18];
  const float* mWv  = (const float*)d_in[19];
  const float* mbv  = (const float*)d_in[20];
  const float* mWo  = (const float*)d_in[21];
  const float* mbo  = (const float*)d_in[22];
  const float* finW = (const float*)d_in[23];
  const float* finb = (const float*)d_in[24];
  (void)in_sizes; (void)n_in; (void)out_size; (void)ws_size;

  char* wp = (char*)d_ws;
  size_t off = 0;
  auto alloc = [&](size_t bytes) -> char* {
    char* p = wp + off;
    off += (bytes + 255) & ~(size_t)255;
    return p;
  };
  u16* h_bf     = (u16*)alloc(1024 * 256 * 2);
  float* hWiWjf = (float*)alloc((size_t)1024 * 512 * 4);
  u16* BtWiWj   = (u16*)alloc(512 * 256 * 2);
  u16* W2t      = (u16*)alloc(256 * 256 * 2);
  u16* Btgn1    = (u16*)alloc(256 * 256 * 2);
  u16* Btgn2    = (u16*)alloc(256 * 256 * 2);
  u16* Btgo     = (u16*)alloc(256 * 256 * 2);
  u16* Btq0     = (u16*)alloc(256 * 256 * 2);
  u16* Btkv0    = (u16*)alloc(512 * 256 * 2);
  u16* Btqkv1   = (u16*)alloc(768 * 256 * 2);
  u16* Btqkv2   = (u16*)alloc(768 * 256 * 2);
  u16* Bto0     = (u16*)alloc(256 * 256 * 2);
  u16* Bto1     = (u16*)alloc(256 * 256 * 2);
  u16* Bto2     = (u16*)alloc(256 * 256 * 2);
  u16* Btfin    = (u16*)alloc(384 * 256 * 2);
  float* bkv0   = (float*)alloc(512 * 4);
  float* bqkv1  = (float*)alloc(768 * 4);
  float* bqkv2  = (float*)alloc(768 * 4);
  u16* q1b      = (u16*)alloc(16 * 256 * 2);
  u16* agg_b    = (u16*)alloc(1024 * 256 * 2);
  u16* n1b      = (u16*)alloc(1024 * 256 * 2);
  u16* n2b      = (u16*)alloc(1024 * 256 * 2);
  u16* encb     = (u16*)alloc(1024 * 256 * 2);
  u16* kv1      = (u16*)alloc(1024 * 512 * 2);
  float* o1f    = (float*)alloc(64 * 256 * 4);
  u16* o1b      = (u16*)alloc(64 * 256 * 2);
  u16* o1pb     = (u16*)alloc(64 * 256 * 2);
  u16* qkv2b    = (u16*)alloc(64 * 768 * 2);
  float* o2f    = (float*)alloc(64 * 256 * 4);
  u16* o2b      = (u16*)alloc(64 * 256 * 2);
  u16* o2pb     = (u16*)alloc(64 * 256 * 2);
  u16* qkv3b    = (u16*)alloc(64 * 768 * 2);
  float* o3f    = (float*)alloc(64 * 256 * 4);
  u16* o3b      = (u16*)alloc(64 * 256 * 2);
  u16* o3pb     = (u16*)alloc(64 * 256 * 2);
  int* bar      = (int*)alloc(256);

  PreArgs P{};
  int nj = 0, tiles = 0;
  auto addJ = [&](const float* s, u16* d, int ncols) {
    P.J.src[nj] = s; P.J.dst[nj] = d; P.J.ncols[nj] = ncols; P.J.tilebase[nj] = tiles;
    tiles += 8 * (ncols / 32); nj++;
  };
  addJ(geW1, BtWiWj, 256);
  addJ(geW1 + 65536, BtWiWj + 65536, 256);
  addJ(geW2, W2t, 256);
  addJ(gnW1, Btgn1, 256);
  addJ(gnW2, Btgn2, 256);
  addJ(goW, Btgo, 256);
  addJ(mWq, Btq0, 256);
  addJ(mWk, Btkv0, 256);
  addJ(mWv, Btkv0 + 65536, 256);
  addJ(mWq + 65536, Btqkv1, 256);
  addJ(mWk + 65536, Btqkv1 + 65536, 256);
  addJ(mWv + 65536, Btqkv1 + 131072, 256);
  addJ(mWq + 131072, Btqkv2, 256);
  addJ(mWk + 131072, Btqkv2 + 65536, 256);
  addJ(mWv + 131072, Btqkv2 + 131072, 256);
  addJ(mWo, Bto0, 256);
  addJ(mWo + 65536, Bto1, 256);
  addJ(mWo + 131072, Bto2, 256);
  addJ(finW, Btfin, 384);
  P.J.njobs = nj;
  P.trTiles = tiles;
  P.hBase = tiles;
  P.prepBid = tiles + 256;
  P.q1Bid = tiles + 257;
  P.x = x; P.ginW = ginW; P.ginb = ginb; P.h_bf = h_bf;
  P.mbk = mbk; P.mbv = mbv; P.mbq = mbq; P.S = S; P.mWq = mWq;
  P.bkv0 = bkv0; P.bqkv1 = bqkv1; P.bqkv2 = bqkv2; P.q1b = q1b;

  TailArgs T{};
  T.agg = agg_b; T.Btgn1 = Btgn1; T.Btgn2 = Btgn2; T.Btgo = Btgo;
  T.Btkv0 = Btkv0; T.Btqkv1 = Btqkv1; T.Btqkv2 = Btqkv2;
  T.Bto0 = Bto0; T.Bto1 = Bto1; T.Bto2 = Bto2; T.Btfin = Btfin; T.q1b = q1b;
  T.gnb1 = gnb1; T.gnb2 = gnb2; T.gob = gob;
  T.bkv0 = bkv0; T.bqkv1 = bqkv1; T.bqkv2 = bqkv2; T.mbo = mbo; T.finb = finb;
  T.n1b = n1b; T.n2b = n2b; T.encb = encb; T.kv1 = kv1;
  T.o1b = o1b; T.o1pb = o1pb; T.qkv2b = qkv2b; T.o2b = o2b; T.o2pb = o2pb;
  T.qkv3b = qkv3b; T.o3b = o3b; T.o3pb = o3pb;
  T.o1f = o1f; T.o2f = o2f; T.o3f = o3f; T.outF = (float*)d_out;
  T.bar = bar;

  hipMemsetAsync(bar, 0, 256, stream);
  k_pre<<<dim3(tiles + 258), dim3(256), 0, stream>>>(P);
  k_gemm<<<dim3(16, 4), dim3(256), 0, stream>>>(h_bf, BtWiWj, nullptr, nullptr, hWiWjf, nullptr, 1024, 512, 0);
  k_edge<<<dim3(1024), dim3(256), 0, stream>>>(hWiWjf, adj, geb1, W2t, geb2, agg_b);
  k_tail<<<dim3(NBLK), dim3(256), 0, stream>>>(T);
}

// Round 7
// 274.798 us; speedup vs baseline: 1.4220x; 1.4173x over previous
//
#include <hip/hip_runtime.h>

typedef unsigned short u16;
typedef __bf16 bf8v __attribute__((ext_vector_type(8)));
typedef float f4v __attribute__((ext_vector_type(4)));

__device__ __forceinline__ float b2f(u16 v) {
  union { unsigned u; float f; } x; x.u = ((unsigned)v) << 16; return x.f;
}
__device__ __forceinline__ u16 f2b(float f) {
  union { float f; unsigned u; } x; x.f = f;
  unsigned r = (x.u + 0x7FFFu + ((x.u >> 16) & 1u)) >> 16;
  return (u16)r;
}
__device__ __forceinline__ void up2(unsigned u, float& lo, float& hi) {
  union { unsigned x; float f; } a, b;
  a.x = u << 16; b.x = u & 0xffff0000u; lo = a.f; hi = b.f;
}

// ---------------------------------------------------------------------------
// Fragment-major weight layout: for weight W[k=0..255][n], tile T=n>>4:
// frag[((T*8+kt)*64+lane)*8 + j] = bf16(W[kt*32+(lane>>4)*8+j][T*16+(lane&15)])
// -> B-fragment load for MFMA 16x16x32 is ONE coalesced 16B/lane read.
// ---------------------------------------------------------------------------
#define NFRAG 19
struct PreArgs {
  const float* fsrc[NFRAG];
  u16* fdst[NFRAG];
  int fstride[NFRAG];
  int fbase[NFRAG + 1];
  int fragTiles, hBase, prepBid, q1Bid;
  const float *x, *ginW, *ginb;
  u16* h_bf;
  const float *mbk, *mbv, *mbq, *S, *mWq;
  float *bkv0, *bqkv1, *bqkv2;
  u16* q1b;
};

__global__ __launch_bounds__(256) void k_pre(PreArgs a) {
  __shared__ u16 ld[256 * 20];
  __shared__ float xs[4][48];
  __shared__ float Ss[4096];
  const int bid = blockIdx.x, t = threadIdx.x;

  if (bid < a.fragTiles) {  // ---- fragize one 16-col tile of a weight ----
    int j = 0;
    while (j + 1 < NFRAG && a.fbase[j + 1] <= bid) j++;
    const int localT = bid - a.fbase[j];
    const float* src = a.fsrc[j];
    const int Ns = a.fstride[j];
    const int n0 = localT * 16;
    {
      const float* s = src + (size_t)t * Ns + n0;
      const float4 v0 = ((const float4*)s)[0], v1 = ((const float4*)s)[1];
      const float4 v2 = ((const float4*)s)[2], v3 = ((const float4*)s)[3];
      u16* row = ld + t * 20;
      row[0] = f2b(v0.x); row[1] = f2b(v0.y); row[2] = f2b(v0.z); row[3] = f2b(v0.w);
      row[4] = f2b(v1.x); row[5] = f2b(v1.y); row[6] = f2b(v1.z); row[7] = f2b(v1.w);
      row[8] = f2b(v2.x); row[9] = f2b(v2.y); row[10] = f2b(v2.z); row[11] = f2b(v2.w);
      row[12] = f2b(v3.x); row[13] = f2b(v3.y); row[14] = f2b(v3.z); row[15] = f2b(v3.w);
    }
    __syncthreads();
    u16* dst = a.fdst[j] + (size_t)localT * 4096;
#pragma unroll
    for (int s2 = 0; s2 < 2; s2++) {
      const int o = t * 2 + s2, kt = o >> 6, lane = o & 63;
      const int nlo = lane & 15, bk = kt * 32 + ((lane >> 4) << 3);
      union { u16 h[8]; uint4 q; } pk;
#pragma unroll
      for (int j2 = 0; j2 < 8; j2++) pk.h[j2] = ld[(bk + j2) * 20 + nlo];
      *(uint4*)(dst + (size_t)(kt * 64 + lane) * 8) = pk.q;
    }
    return;
  }
  if (bid >= a.hBase && bid < a.hBase + 256) {  // ---- h projection ----
    const int row0 = (bid - a.hBase) * 4;
    if (t < 192) {
      const int rr = t / 48, k = t % 48;
      xs[rr][k] = a.x[(size_t)(row0 + rr) * 48 + k];
    }
    __syncthreads();
    const float bias = a.ginb[t];
    float acc[4] = {bias, bias, bias, bias};
    for (int k = 0; k < 48; k++) {
      const float w = a.ginW[(size_t)k * 256 + t];
#pragma unroll
      for (int rr = 0; rr < 4; rr++) acc[rr] += xs[rr][k] * w;
    }
#pragma unroll
    for (int rr = 0; rr < 4; rr++) a.h_bf[(size_t)(row0 + rr) * 256 + t] = f2b(acc[rr]);
    return;
  }
  if (bid == a.prepBid) {  // ---- bias concat ----
    a.bkv0[t] = a.mbk[t]; a.bkv0[256 + t] = a.mbv[t];
    a.bqkv1[t] = a.mbq[256 + t]; a.bqkv1[256 + t] = a.mbk[256 + t]; a.bqkv1[512 + t] = a.mbv[256 + t];
    a.bqkv2[t] = a.mbq[512 + t]; a.bqkv2[256 + t] = a.mbk[512 + t]; a.bqkv2[512 + t] = a.mbv[512 + t];
    return;
  }
  if (bid == a.q1Bid) {  // ---- q1 = S @ Wq0 + bq0 (fp32 vector, one block) ----
    for (int idx = t; idx < 4096; idx += 256) Ss[idx] = a.S[idx];
    __syncthreads();
    float acc[16];
#pragma unroll
    for (int r = 0; r < 16; r++) acc[r] = 0.f;
    for (int k = 0; k < 256; k++) {
      const float w = a.mWq[(size_t)k * 256 + t];
#pragma unroll
      for (int r = 0; r < 16; r++) acc[r] += Ss[r * 256 + k] * w;
    }
    const float bq = a.mbq[t];
#pragma unroll
    for (int r = 0; r < 16; r++) a.q1b[r * 256 + t] = f2b(acc[r] + bq);
    return;
  }
}

// ---------------------------------------------------------------------------
// hWiWj GEMM: A (1024x256 bf16) x fragWiWj (N=512) -> fp32. A staged once.
// ---------------------------------------------------------------------------
__global__ __launch_bounds__(256) void k_wiwj(
    const u16* __restrict__ h, const u16* __restrict__ frag, float* __restrict__ out) {
  __shared__ __align__(16) u16 As[64 * 264];
  const int t = threadIdx.x, lane = t & 63, wv = t >> 6;
  const int m0 = blockIdx.x * 64, n0 = blockIdx.y * 128;
  {
    const int row = t >> 2, ch = t & 3;
#pragma unroll
    for (int s = 0; s < 8; s++)
      *(uint4*)(As + row * 264 + ch * 64 + s * 8) =
          *(const uint4*)(h + (size_t)(m0 + row) * 256 + ch * 64 + s * 8);
  }
  __syncthreads();
  f4v acc[4][2];
#pragma unroll
  for (int mt = 0; mt < 4; mt++)
#pragma unroll
    for (int nt = 0; nt < 2; nt++) acc[mt][nt] = (f4v){0.f, 0.f, 0.f, 0.f};
  const int Tw = (n0 >> 4) + wv * 2;
#pragma unroll
  for (int kt = 0; kt < 8; kt++) {
    bf8v af[4], bf[2];
#pragma unroll
    for (int mt = 0; mt < 4; mt++)
      af[mt] = *(const bf8v*)(As + (mt * 16 + (lane & 15)) * 264 + kt * 32 + ((lane >> 4) << 3));
#pragma unroll
    for (int nt = 0; nt < 2; nt++)
      bf[nt] = *(const bf8v*)(frag + ((size_t)((Tw + nt) * 8 + kt) * 64 + lane) * 8);
#pragma unroll
    for (int mt = 0; mt < 4; mt++)
#pragma unroll
      for (int nt = 0; nt < 2; nt++)
        acc[mt][nt] = __builtin_amdgcn_mfma_f32_16x16x32_bf16(af[mt], bf[nt], acc[mt][nt], 0, 0, 0);
  }
#pragma unroll
  for (int mt = 0; mt < 4; mt++)
#pragma unroll
    for (int nt = 0; nt < 2; nt++) {
      const int n = n0 + wv * 32 + nt * 16 + (lane & 15);
      const int mb = m0 + mt * 16 + ((lane >> 4) << 2);
#pragma unroll
      for (int r = 0; r < 4; r++) out[(size_t)(mb + r) * 512 + n] = acc[mt][nt][r];
    }
}

// ---------------------------------------------------------------------------
// Edge MLP + masked aggregation: frag-major W2 (coalesced B), register B-frags,
// zero barriers in kt loop.
// ---------------------------------------------------------------------------
__global__ __launch_bounds__(256, 2) void k_edge(
    const float* __restrict__ hWiWj, const float* __restrict__ adj,
    const float* __restrict__ geb1, const u16* __restrict__ fragW2,
    const float* __restrict__ geb2, u16* __restrict__ aggB) {
  __shared__ __align__(16) u16 As[64 * 264];
  __shared__ float hi[256];
  __shared__ int jlist[256];
  __shared__ int cnt;
  const int t = threadIdx.x, lane = t & 63, wv = t >> 6;
  const int b = blockIdx.x >> 8, i = blockIdx.x & 255;
  if (t == 0) cnt = 0;
  __syncthreads();
  {
    const float a = adj[(size_t)(b * 256 + i) * 256 + t];
    hi[t] = hWiWj[(size_t)(b * 256 + i) * 512 + t] + geb1[t];
    if (a != 0.f) { const int p = atomicAdd(&cnt, 1); jlist[p] = t; }
  }
  __syncthreads();
  const int nact = cnt;
  if (nact == 0) {
    if (lane < 16) {
#pragma unroll
      for (int nt = 0; nt < 4; nt++)
        aggB[(size_t)(b * 256 + i) * 256 + wv * 64 + nt * 16 + lane] = 0;
    }
    return;
  }
  const int nch = (nact + 63) >> 6;
  float bias2[4];
#pragma unroll
  for (int nt = 0; nt < 4; nt++) bias2[nt] = geb2[wv * 64 + nt * 16 + (lane & 15)];
  float aggAcc[4] = {0.f, 0.f, 0.f, 0.f};
  const u16* fw = fragW2 + lane * 8;  // + (T*8+kt)*512

  for (int c = 0; c < nch; c++) {
    const int rows = min(64, nact - c * 64);
    {  // build A chunk: relu(hWi + hWj[j] + geb1) -> bf16
      const int r = t >> 2, q = t & 3;
      const bool valid = (r < rows);
      const int j = valid ? jlist[c * 64 + r] : jlist[0];
      const float4* s4 = (const float4*)(hWiWj + (size_t)(b * 256 + j) * 512 + 256 + q * 64);
      u16* dstrow = As + r * 264 + q * 64;
#pragma unroll
      for (int ii = 0; ii < 8; ii++) {
        const float4 v0 = s4[ii * 2];
        const float4 v1 = s4[ii * 2 + 1];
        const int k = q * 64 + ii * 8;
        union { u16 s[8]; uint4 qd; } pk;
        pk.s[0] = f2b(fmaxf(v0.x + hi[k + 0], 0.f));
        pk.s[1] = f2b(fmaxf(v0.y + hi[k + 1], 0.f));
        pk.s[2] = f2b(fmaxf(v0.z + hi[k + 2], 0.f));
        pk.s[3] = f2b(fmaxf(v0.w + hi[k + 3], 0.f));
        pk.s[4] = f2b(fmaxf(v1.x + hi[k + 4], 0.f));
        pk.s[5] = f2b(fmaxf(v1.y + hi[k + 5], 0.f));
        pk.s[6] = f2b(fmaxf(v1.z + hi[k + 6], 0.f));
        pk.s[7] = f2b(fmaxf(v1.w + hi[k + 7], 0.f));
        *(uint4*)(dstrow + ii * 8) = pk.qd;
      }
    }
    __syncthreads();
    f4v acc[4][4];
#pragma unroll
    for (int jt = 0; jt < 4; jt++)
#pragma unroll
      for (int nt = 0; nt < 4; nt++) acc[jt][nt] = (f4v){0.f, 0.f, 0.f, 0.f};
    bf8v bcur[4];
#pragma unroll
    for (int nt = 0; nt < 4; nt++)
      bcur[nt] = *(const bf8v*)(fw + (size_t)((wv * 4 + nt) * 8 + 0) * 512);
#pragma unroll
    for (int kt = 0; kt < 8; kt++) {
      bf8v bnxt[4];
      if (kt < 7) {
#pragma unroll
        for (int nt = 0; nt < 4; nt++)
          bnxt[nt] = *(const bf8v*)(fw + (size_t)((wv * 4 + nt) * 8 + kt + 1) * 512);
      }
      bf8v af[4];
#pragma unroll
      for (int jt = 0; jt < 4; jt++)
        af[jt] = *(const bf8v*)(As + (jt * 16 + (lane & 15)) * 264 + kt * 32 + ((lane >> 4) << 3));
#pragma unroll
      for (int nt = 0; nt < 4; nt++)
#pragma unroll
        for (int jt = 0; jt < 4; jt++)
          acc[jt][nt] = __builtin_amdgcn_mfma_f32_16x16x32_bf16(af[jt], bcur[nt], acc[jt][nt], 0, 0, 0);
      if (kt < 7) {
#pragma unroll
        for (int nt = 0; nt < 4; nt++) bcur[nt] = bnxt[nt];
      }
    }
    const int rbase = (lane >> 4) * 4;
#pragma unroll
    for (int nt = 0; nt < 4; nt++) {
      float s = 0.f;
#pragma unroll
      for (int jt = 0; jt < 4; jt++) {
        const int r0 = jt * 16 + rbase;
#pragma unroll
        for (int r = 0; r < 4; r++) {
          const float e = fmaxf(acc[jt][nt][r] + bias2[nt], 0.f);
          s += (r0 + r < rows) ? e : 0.f;
        }
      }
      s += __shfl_xor(s, 16);
      s += __shfl_xor(s, 32);
      aggAcc[nt] += s;
    }
    __syncthreads();
  }
  if (lane < 16) {
#pragma unroll
    for (int nt = 0; nt < 4; nt++) {
      const int n = wv * 64 + nt * 16 + lane;
      aggB[(size_t)(b * 256 + i) * 256 + n] = f2b(aggAcc[nt]);
    }
  }
}

// ---------------------------------------------------------------------------
// Fused tail, 32 persistent blocks, TWO grid barriers.
// ---------------------------------------------------------------------------
#define NBLK 32

__device__ __forceinline__ void gridbar(int* cnt, int gen) {
  __syncthreads();
  if (threadIdx.x == 0) {
    __threadfence();
    __hip_atomic_fetch_add(cnt, 1, __ATOMIC_RELAXED, __HIP_MEMORY_SCOPE_AGENT);
    int it = 0;
    while (__hip_atomic_load(cnt, __ATOMIC_RELAXED, __HIP_MEMORY_SCOPE_AGENT) < NBLK * gen) {
      __builtin_amdgcn_s_sleep(8);
      if (((++it) & 255) == 0)
        __hip_atomic_fetch_add(cnt, 0, __ATOMIC_RELAXED, __HIP_MEMORY_SCOPE_AGENT);
    }
    __threadfence();
  }
  __syncthreads();
}

// M=32 GEMM, A in LDS (stride 264), frag-major B, out LDS bf16 (stride 264)
__device__ void g32(const u16* Al, const u16* frag, const float* bias, int relu,
                    u16* Ol, int t) {
  const int lane = t & 63, wv = t >> 6;
  f4v acc[2][4];
#pragma unroll
  for (int mt = 0; mt < 2; mt++)
#pragma unroll
    for (int nt = 0; nt < 4; nt++) acc[mt][nt] = (f4v){0.f, 0.f, 0.f, 0.f};
#pragma unroll
  for (int kt = 0; kt < 8; kt++) {
    bf8v af[2], bf[4];
#pragma unroll
    for (int mt = 0; mt < 2; mt++)
      af[mt] = *(const bf8v*)(Al + (mt * 16 + (lane & 15)) * 264 + kt * 32 + ((lane >> 4) << 3));
#pragma unroll
    for (int nt = 0; nt < 4; nt++)
      bf[nt] = *(const bf8v*)(frag + ((size_t)((wv * 4 + nt) * 8 + kt) * 64 + lane) * 8);
#pragma unroll
    for (int mt = 0; mt < 2; mt++)
#pragma unroll
      for (int nt = 0; nt < 4; nt++)
        acc[mt][nt] = __builtin_amdgcn_mfma_f32_16x16x32_bf16(af[mt], bf[nt], acc[mt][nt], 0, 0, 0);
  }
#pragma unroll
  for (int mt = 0; mt < 2; mt++)
#pragma unroll
    for (int nt = 0; nt < 4; nt++) {
      const int col = wv * 64 + nt * 16 + (lane & 15);
      const float bv = bias[col];
#pragma unroll
      for (int r = 0; r < 4; r++) {
        const int row = mt * 16 + ((lane >> 4) << 2) + r;
        float v = acc[mt][nt][r] + bv;
        if (relu) v = fmaxf(v, 0.f);
        Ol[row * 264 + col] = f2b(v);
      }
    }
}

// M=32, N=512 GEMM -> global bf16 (kv1)
__device__ void g32kv(const u16* Al, const u16* frag, const float* bias,
                      u16* outG, int t) {
  const int lane = t & 63, wv = t >> 6;
  f4v acc[2][8];
#pragma unroll
  for (int mt = 0; mt < 2; mt++)
#pragma unroll
    for (int nt = 0; nt < 8; nt++) acc[mt][nt] = (f4v){0.f, 0.f, 0.f, 0.f};
#pragma unroll
  for (int kt = 0; kt < 8; kt++) {
    bf8v af[2];
#pragma unroll
    for (int mt = 0; mt < 2; mt++)
      af[mt] = *(const bf8v*)(Al + (mt * 16 + (lane & 15)) * 264 + kt * 32 + ((lane >> 4) << 3));
#pragma unroll
    for (int nt = 0; nt < 8; nt++) {
      const bf8v bf = *(const bf8v*)(frag + ((size_t)((wv * 8 + nt) * 8 + kt) * 64 + lane) * 8);
#pragma unroll
      for (int mt = 0; mt < 2; mt++)
        acc[mt][nt] = __builtin_amdgcn_mfma_f32_16x16x32_bf16(af[mt], bf, acc[mt][nt], 0, 0, 0);
    }
  }
#pragma unroll
  for (int mt = 0; mt < 2; mt++)
#pragma unroll
    for (int nt = 0; nt < 8; nt++) {
      const int col = wv * 128 + nt * 16 + (lane & 15);
      const float bv = bias[col];
#pragma unroll
      for (int r = 0; r < 4; r++) {
        const int row = mt * 16 + ((lane >> 4) << 2) + r;
        outG[(size_t)row * 512 + col] = f2b(acc[mt][nt][r] + bv);
      }
    }
}

// M=16 GEMM; mode 1: v=relu(v)+resid; outputs to LDS bf16 and/or global fp32.
template <int NT>
__device__ void g16(const u16* Al, const u16* frag, const float* bias, int mode,
                    const float* residL, u16* OlBf, int olstride,
                    float* outG, int ostride, int t) {
  const int lane = t & 63, wv = t >> 6;
  f4v acc[NT];
#pragma unroll
  for (int nt = 0; nt < NT; nt++) acc[nt] = (f4v){0.f, 0.f, 0.f, 0.f};
#pragma unroll
  for (int kt = 0; kt < 8; kt++) {
    const bf8v af = *(const bf8v*)(Al + (lane & 15) * 264 + kt * 32 + ((lane >> 4) << 3));
#pragma unroll
    for (int nt = 0; nt < NT; nt++) {
      const bf8v bf = *(const bf8v*)(frag + ((size_t)((wv * NT + nt) * 8 + kt) * 64 + lane) * 8);
      acc[nt] = __builtin_amdgcn_mfma_f32_16x16x32_bf16(af, bf, acc[nt], 0, 0, 0);
    }
  }
#pragma unroll
  for (int nt = 0; nt < NT; nt++) {
    const int col = wv * (NT * 16) + nt * 16 + (lane & 15);
    const float bv = bias[col];
#pragma unroll
    for (int r = 0; r < 4; r++) {
      const int row = ((lane >> 4) << 2) + r;
      float v = acc[nt][r] + bv;
      if (mode == 1) v = fmaxf(v, 0.f) + residL[row * 256 + col];
      if (OlBf) OlBf[row * olstride + col] = f2b(v);
      if (outG) outG[(size_t)row * ostride + col] = v;
    }
  }
}

// attn1 helper (Lk=256), one (b,hd) per block — verified round-5/6 code.
__device__ void attn_tile(const u16* __restrict__ qbuf, int qstride, int qshared,
                          const u16* __restrict__ kbuf, const u16* __restrict__ vbuf,
                          int kvstride, int Lk,
                          float* __restrict__ oF, u16* __restrict__ oB,
                          int b, int hd, float* qs, float* sc, float* vs, int t) {
  const int lane = t & 63, wv = t >> 6;
  for (int idx = t; idx < 512; idx += 256) {
    const int r = idx >> 5, d = idx & 31;
    const int qrow = qshared ? r : (b * 16 + r);
    qs[r * 32 + d] = b2f(qbuf[(size_t)qrow * qstride + hd * 32 + d]);
  }
  __syncthreads();
  if (t < Lk) {
    float kv[32];
#pragma unroll
    for (int d = 0; d < 32; d++) kv[d] = b2f(kbuf[(size_t)(b * Lk + t) * kvstride + hd * 32 + d]);
    for (int r = 0; r < 16; r++) {
      float s = 0.f;
#pragma unroll
      for (int d = 0; d < 32; d++) s += qs[r * 32 + d] * kv[d];
      sc[r * 256 + t] = s * 0.0625f;
    }
  }
  __syncthreads();
  for (int r = wv * 4; r < wv * 4 + 4; r++) {
    float v[4];
    float mx = -1e30f;
#pragma unroll
    for (int q2 = 0; q2 < 4; q2++) {
      const int j = lane + q2 * 64;
      v[q2] = (j < Lk) ? sc[r * 256 + j] : -1e30f;
      mx = fmaxf(mx, v[q2]);
    }
    for (int off = 32; off; off >>= 1) mx = fmaxf(mx, __shfl_xor(mx, off));
    float sum = 0.f;
#pragma unroll
    for (int q2 = 0; q2 < 4; q2++) {
      v[q2] = (lane + q2 * 64 < Lk) ? __expf(v[q2] - mx) : 0.f;
      sum += v[q2];
    }
    for (int off = 32; off; off >>= 1) sum += __shfl_xor(sum, off);
    const float inv = 1.f / sum;
#pragma unroll
    for (int q2 = 0; q2 < 4; q2++) {
      const int j = lane + q2 * 64;
      if (j < Lk) sc[r * 256 + j] = v[q2] * inv;
    }
  }
  __syncthreads();
  for (int idx = t; idx < Lk * 32; idx += 256)
    vs[idx] = b2f(vbuf[(size_t)(b * Lk + (idx >> 5)) * kvstride + hd * 32 + (idx & 31)]);
  __syncthreads();
  const int r0 = t >> 5, d = t & 31;
  float a0 = qs[r0 * 32 + d], a1 = qs[(r0 + 8) * 32 + d];
  for (int j = 0; j < Lk; j++) {
    const float vv = vs[j * 32 + d];
    a0 += sc[r0 * 256 + j] * vv;
    a1 += sc[(r0 + 8) * 256 + j] * vv;
  }
  const int c0 = hd * 32 + d;
  oF[(size_t)(b * 16 + r0) * 256 + c0] = a0;
  oB[(size_t)(b * 16 + r0) * 256 + c0] = f2b(a0);
  oF[(size_t)(b * 16 + r0 + 8) * 256 + c0] = a1;
  oB[(size_t)(b * 16 + r0 + 8) * 256 + c0] = f2b(a1);
}

// In-block attention for Lk=16 (mab2/3): qkv in LDS (stride 776), out->resid+act
__device__ void attn_block(const u16* qkv, float* resid, u16* actA, float* ps, int t) {
  const int lane = t & 63, wv = t >> 6;
  const int r = lane & 15, cg = lane >> 4;
#pragma unroll 1
  for (int hh = 0; hh < 2; hh++) {
    const int hd = wv + hh * 4;
    float qv[32];
    {
      const uint4* qp = (const uint4*)(qkv + r * 776 + hd * 32);
#pragma unroll
      for (int c4 = 0; c4 < 4; c4++) {
        const uint4 q4 = qp[c4];
        up2(q4.x, qv[c4 * 8 + 0], qv[c4 * 8 + 1]);
        up2(q4.y, qv[c4 * 8 + 2], qv[c4 * 8 + 3]);
        up2(q4.z, qv[c4 * 8 + 4], qv[c4 * 8 + 5]);
        up2(q4.w, qv[c4 * 8 + 6], qv[c4 * 8 + 7]);
      }
    }
    float p[4];
#pragma unroll
    for (int c = 0; c < 4; c++) {
      const int cc = cg * 4 + c;
      const uint4* kp = (const uint4*)(qkv + cc * 776 + 256 + hd * 32);
      float s = 0.f;
#pragma unroll
      for (int c4 = 0; c4 < 4; c4++) {
        const uint4 k4 = kp[c4];
        float k0, k1;
        up2(k4.x, k0, k1); s += qv[c4 * 8 + 0] * k0 + qv[c4 * 8 + 1] * k1;
        up2(k4.y, k0, k1); s += qv[c4 * 8 + 2] * k0 + qv[c4 * 8 + 3] * k1;
        up2(k4.z, k0, k1); s += qv[c4 * 8 + 4] * k0 + qv[c4 * 8 + 5] * k1;
        up2(k4.w, k0, k1); s += qv[c4 * 8 + 6] * k0 + qv[c4 * 8 + 7] * k1;
      }
      p[c] = s * 0.0625f;
    }
    float mx = fmaxf(fmaxf(p[0], p[1]), fmaxf(p[2], p[3]));
    mx = fmaxf(mx, __shfl_xor(mx, 16));
    mx = fmaxf(mx, __shfl_xor(mx, 32));
    float sum = 0.f;
#pragma unroll
    for (int c = 0; c < 4; c++) { p[c] = __expf(p[c] - mx); sum += p[c]; }
    sum += __shfl_xor(sum, 16);
    sum += __shfl_xor(sum, 32);
    const float inv = 1.f / sum;
    __syncthreads();
#pragma unroll
    for (int c = 0; c < 4; c++) ps[wv * 256 + r * 16 + cg * 4 + c] = p[c] * inv;
    __syncthreads();
    float o[8];
#pragma unroll
    for (int j = 0; j < 8; j++) o[j] = qv[cg * 8 + j];
#pragma unroll
    for (int c = 0; c < 16; c++) {
      const float pv = ps[wv * 256 + r * 16 + c];
      const uint4 v4 = *(const uint4*)(qkv + c * 776 + 512 + hd * 32 + cg * 8);
      float v0, v1;
      up2(v4.x, v0, v1); o[0] += pv * v0; o[1] += pv * v1;
      up2(v4.y, v0, v1); o[2] += pv * v0; o[3] += pv * v1;
      up2(v4.z, v0, v1); o[4] += pv * v0; o[5] += pv * v1;
      up2(v4.w, v0, v1); o[6] += pv * v0; o[7] += pv * v1;
    }
#pragma unroll
    for (int j = 0; j < 8; j++) {
      const int col = hd * 32 + cg * 8 + j;
      resid[r * 256 + col] = o[j];
      actA[r * 264 + col] = f2b(o[j]);
    }
  }
}

struct TailArgs {
  const u16 *agg, *fGn1, *fGn2, *fGo, *fKV0, *fQKV1, *fQKV2, *fO0, *fO1, *fO2, *fFin, *q1b;
  const float *gnb1, *gnb2, *gob, *bkv0, *bqkv1, *bqkv2, *mbo, *finb;
  u16 *kv1, *o1b;
  float *o1f, *outF;
  int* bar;
};

__global__ __launch_bounds__(256) void k_tail(TailArgs a) {
  __shared__ __align__(16) char smem[63488];
  const int bid = blockIdx.x, t = threadIdx.x;

  {  // ---- phase 1: rows bid*32..+31: agg -> n1 -> n2 -> enc -> kv1 ----
    u16* actA = (u16*)smem;
    u16* actB = (u16*)(smem + 16896);
    const int r0 = bid * 32;
#pragma unroll
    for (int s = 0; s < 4; s++) {
      const int u = t * 4 + s, row = u >> 5, ch = u & 31;
      *(uint4*)(actA + row * 264 + ch * 8) =
          *(const uint4*)(a.agg + (size_t)(r0 + row) * 256 + ch * 8);
    }
    __syncthreads();
    g32(actA, a.fGn1, a.gnb1, 1, actB, t); __syncthreads();
    g32(actB, a.fGn2, a.gnb2, 1, actA, t); __syncthreads();
    g32(actA, a.fGo, a.gob, 0, actB, t); __syncthreads();
    g32kv(actB, a.fKV0, a.bkv0, a.kv1 + (size_t)r0 * 512, t);
  }
  gridbar(a.bar, 1);
  {  // ---- phase 2: attn1, one (b,hd) per block ----
    float* qs = (float*)smem;
    float* sc = (float*)(smem + 2048);
    float* vs = (float*)(smem + 18432);
    attn_tile(a.q1b, 256, 1, a.kv1, a.kv1 + 256, 512, 256, a.o1f, a.o1b,
              bid >> 3, bid & 7, qs, sc, vs, t);
  }
  gridbar(a.bar, 2);
  if (bid >= 4) return;
  {  // ---- phase 3: block b owns rows b*16..+15 through mab2+mab3+final ----
    u16* actA = (u16*)smem;                    // 8448
    u16* actB = (u16*)(smem + 8448);           // 8448
    u16* qkv = (u16*)(smem + 16896);           // 24832
    float* resid = (float*)(smem + 41728);     // 16384
    float* ps = (float*)(smem + 58112);        // 4096
    const int row0 = bid * 16;
#pragma unroll
    for (int s = 0; s < 4; s++) {
      const int u = t * 4 + s, row = u >> 6, ch = u & 63;
      const float4 v = *(const float4*)(a.o1f + (size_t)(row0 + row) * 256 + ch * 4);
      *(float4*)(resid + row * 256 + ch * 4) = v;
      u16* d = actA + row * 264 + ch * 4;
      d[0] = f2b(v.x); d[1] = f2b(v.y); d[2] = f2b(v.z); d[3] = f2b(v.w);
    }
    __syncthreads();
    g16<4>(actA, a.fO0, a.mbo, 1, resid, actB, 264, nullptr, 0, t); __syncthreads();
    g16<12>(actB, a.fQKV1, a.bqkv1, 0, nullptr, qkv, 776, nullptr, 0, t); __syncthreads();
    attn_block(qkv, resid, actA, ps, t); __syncthreads();
    g16<4>(actA, a.fO1, a.mbo + 256, 1, resid, actB, 264, nullptr, 0, t); __syncthreads();
    g16<12>(actB, a.fQKV2, a.bqkv2, 0, nullptr, qkv, 776, nullptr, 0, t); __syncthreads();
    attn_block(qkv, resid, actA, ps, t); __syncthreads();
    g16<4>(actA, a.fO2, a.mbo + 512, 1, resid, actB, 264, nullptr, 0, t); __syncthreads();
    g16<6>(actB, a.fFin, a.finb, 0, nullptr, nullptr, 0, a.outF + (size_t)row0 * 384, 384, t);
  }
}

// ---------------------------------------------------------------------------
extern "C" void kernel_launch(void* const* d_in, const int* in_sizes, int n_in,
                              void* d_out, int out_size, void* d_ws, size_t ws_size,
                              hipStream_t stream) {
  const float* x    = (const float*)d_in[0];
  const float* adj  = (const float*)d_in[1];
  const float* ginW = (const float*)d_in[2];
  const float* ginb = (const float*)d_in[3];
  const float* geW1 = (const float*)d_in[4];
  const float* geb1 = (const float*)d_in[5];
  const float* geW2 = (const float*)d_in[6];
  const float* geb2 = (const float*)d_in[7];
  const float* gnW1 = (const float*)d_in[8];
  const float* gnb1 = (const float*)d_in[9];
  const float* gnW2 = (const float*)d_in[10];
  const float* gnb2 = (const float*)d_in[11];
  const float* goW  = (const float*)d_in[12];
  const float* gob  = (const float*)d_in[13];
  const float* S    = (const float*)d_in[14];
  const float* mWq  = (const float*)d_in[15];
  const float* mbq  = (const float*)d_in[16];
  const float* mWk  = (const float*)d_in[17];
  const float* mbk  = (const float*)d_in[18];
  const float* mWv  = (const float*)d_in[19];
  const float* mbv  = (const float*)d_in[20];
  const float* mWo  = (const float*)d_in[21];
  const float* mbo  = (const float*)d_in[22];
  const float* finW = (const float*)d_in[23];
  const float* finb = (const float*)d_in[24];
  (void)in_sizes; (void)n_in; (void)out_size; (void)ws_size;

  char* wp = (char*)d_ws;
  size_t off = 0;
  auto alloc = [&](size_t bytes) -> char* {
    char* p = wp + off;
    off += (bytes + 255) & ~(size_t)255;
    return p;
  };
  u16* h_bf     = (u16*)alloc(1024 * 256 * 2);
  float* hWiWjf = (float*)alloc((size_t)1024 * 512 * 4);
  u16* fWiWj    = (u16*)alloc(512 * 256 * 2);
  u16* fW2      = (u16*)alloc(256 * 256 * 2);
  u16* fGn1     = (u16*)alloc(256 * 256 * 2);
  u16* fGn2     = (u16*)alloc(256 * 256 * 2);
  u16* fGo      = (u16*)alloc(256 * 256 * 2);
  u16* fQ0      = (u16*)alloc(256 * 256 * 2);
  u16* fKV0     = (u16*)alloc(512 * 256 * 2);
  u16* fQKV1    = (u16*)alloc(768 * 256 * 2);
  u16* fQKV2    = (u16*)alloc(768 * 256 * 2);
  u16* fO0      = (u16*)alloc(256 * 256 * 2);
  u16* fO1      = (u16*)alloc(256 * 256 * 2);
  u16* fO2      = (u16*)alloc(256 * 256 * 2);
  u16* fFin     = (u16*)alloc(384 * 256 * 2);
  float* bkv0   = (float*)alloc(512 * 4);
  float* bqkv1  = (float*)alloc(768 * 4);
  float* bqkv2  = (float*)alloc(768 * 4);
  u16* q1b      = (u16*)alloc(16 * 256 * 2);
  u16* agg_b    = (u16*)alloc(1024 * 256 * 2);
  u16* kv1      = (u16*)alloc(1024 * 512 * 2);
  float* o1f    = (float*)alloc(64 * 256 * 4);
  u16* o1b      = (u16*)alloc(64 * 256 * 2);
  int* bar      = (int*)alloc(256);

  PreArgs P{};
  int nj = 0, tiles = 0;
  auto addF = [&](const float* s, int stride, u16* d, int nT) {
    P.fsrc[nj] = s; P.fdst[nj] = d; P.fstride[nj] = stride; P.fbase[nj] = tiles;
    tiles += nT; nj++;
  };
  addF(geW1, 256, fWiWj, 16);
  addF(geW1 + 65536, 256, fWiWj + 16 * 4096, 16);
  addF(geW2, 256, fW2, 16);
  addF(gnW1, 256, fGn1, 16);
  addF(gnW2, 256, fGn2, 16);
  addF(goW, 256, fGo, 16);
  addF(mWq, 256, fQ0, 16);
  addF(mWk, 256, fKV0, 16);
  addF(mWv, 256, fKV0 + 16 * 4096, 16);
  addF(mWq + 65536, 256, fQKV1, 16);
  addF(mWk + 65536, 256, fQKV1 + 16 * 4096, 16);
  addF(mWv + 65536, 256, fQKV1 + 32 * 4096, 16);
  addF(mWq + 131072, 256, fQKV2, 16);
  addF(mWk + 131072, 256, fQKV2 + 16 * 4096, 16);
  addF(mWv + 131072, 256, fQKV2 + 32 * 4096, 16);
  addF(mWo, 256, fO0, 16);
  addF(mWo + 65536, 256, fO1, 16);
  addF(mWo + 131072, 256, fO2, 16);
  addF(finW, 384, fFin, 24);
  P.fbase[nj] = tiles;
  P.fragTiles = tiles;
  P.hBase = tiles;
  P.prepBid = tiles + 256;
  P.q1Bid = tiles + 257;
  P.x = x; P.ginW = ginW; P.ginb = ginb; P.h_bf = h_bf;
  P.mbk = mbk; P.mbv = mbv; P.mbq = mbq; P.S = S; P.mWq = mWq;
  P.bkv0 = bkv0; P.bqkv1 = bqkv1; P.bqkv2 = bqkv2; P.q1b = q1b;

  TailArgs T{};
  T.agg = agg_b; T.fGn1 = fGn1; T.fGn2 = fGn2; T.fGo = fGo; T.fKV0 = fKV0;
  T.fQKV1 = fQKV1; T.fQKV2 = fQKV2; T.fO0 = fO0; T.fO1 = fO1; T.fO2 = fO2;
  T.fFin = fFin; T.q1b = q1b;
  T.gnb1 = gnb1; T.gnb2 = gnb2; T.gob = gob;
  T.bkv0 = bkv0; T.bqkv1 = bqkv1; T.bqkv2 = bqkv2; T.mbo = mbo; T.finb = finb;
  T.kv1 = kv1; T.o1b = o1b; T.o1f = o1f; T.outF = (float*)d_out;
  T.bar = bar;

  hipMemsetAsync(bar, 0, 256, stream);
  k_pre<<<dim3(tiles + 258), dim3(256), 0, stream>>>(P);
  k_wiwj<<<dim3(16, 4), dim3(256), 0, stream>>>(h_bf, fWiWj, hWiWjf);
  k_edge<<<dim3(1024), dim3(256), 0, stream>>>(hWiWjf, adj, geb1, fW2, geb2, agg_b);
  k_tail<<<dim3(NBLK), dim3(256), 0, stream>>>(T);
}

// Round 8
// 266.026 us; speedup vs baseline: 1.4689x; 1.0330x over previous
//
#include <hip/hip_runtime.h>
#include <hip/hip_bf16.h>

typedef unsigned short u16;
typedef __bf16 bf8v __attribute__((ext_vector_type(8)));
typedef float f4v __attribute__((ext_vector_type(4)));

__device__ __forceinline__ float b2f(u16 v) {
  union { unsigned u; float f; } x; x.u = ((unsigned)v) << 16; return x.f;
}
__device__ __forceinline__ u16 f2b(float f) {
  union { float f; unsigned u; } x; x.f = f;
  unsigned r = (x.u + 0x7FFFu + ((x.u >> 16) & 1u)) >> 16;
  return (u16)r;
}
__device__ __forceinline__ unsigned pkbf(float a, float b) {
  union { __hip_bfloat162 h; unsigned u; } c;
  c.h = __float22bfloat162_rn(make_float2(a, b));
  return c.u;
}
__device__ __forceinline__ void up2(unsigned u, float& lo, float& hi) {
  union { unsigned x; float f; } a, b;
  a.x = u << 16; b.x = u & 0xffff0000u; lo = a.f; hi = b.f;
}

// ---------------------------------------------------------------------------
// Fragment-major weight layout: for weight W[k=0..255][n], tile T=n>>4:
// frag[((T*8+kt)*64+lane)*8 + j] = bf16(W[kt*32+(lane>>4)*8+j][T*16+(lane&15)])
// ---------------------------------------------------------------------------
#define NFRAG 19
struct PreArgs {
  const float* fsrc[NFRAG];
  u16* fdst[NFRAG];
  int fstride[NFRAG];
  int fbase[NFRAG + 1];
  int fragTiles, hBase, prepBid, q1Bid;
  const float *x, *ginW, *ginb;
  u16* h_bf;
  const float *mbk, *mbv, *mbq, *S, *mWq;
  float *bkv0, *bqkv1, *bqkv2;
  u16* q1b;
};

__global__ __launch_bounds__(256) void k_pre(PreArgs a) {
  __shared__ u16 ld[256 * 20];
  __shared__ float xs[4][48];
  __shared__ float Ss[4096];
  const int bid = blockIdx.x, t = threadIdx.x;

  if (bid < a.fragTiles) {
    int j = 0;
    while (j + 1 < NFRAG && a.fbase[j + 1] <= bid) j++;
    const int localT = bid - a.fbase[j];
    const float* src = a.fsrc[j];
    const int Ns = a.fstride[j];
    const int n0 = localT * 16;
    {
      const float* s = src + (size_t)t * Ns + n0;
      const float4 v0 = ((const float4*)s)[0], v1 = ((const float4*)s)[1];
      const float4 v2 = ((const float4*)s)[2], v3 = ((const float4*)s)[3];
      unsigned* row = (unsigned*)(ld + t * 20);
      row[0] = pkbf(v0.x, v0.y); row[1] = pkbf(v0.z, v0.w);
      row[2] = pkbf(v1.x, v1.y); row[3] = pkbf(v1.z, v1.w);
      row[4] = pkbf(v2.x, v2.y); row[5] = pkbf(v2.z, v2.w);
      row[6] = pkbf(v3.x, v3.y); row[7] = pkbf(v3.z, v3.w);
    }
    __syncthreads();
    u16* dst = a.fdst[j] + (size_t)localT * 4096;
#pragma unroll
    for (int s2 = 0; s2 < 2; s2++) {
      const int o = t * 2 + s2, kt = o >> 6, lane = o & 63;
      const int nlo = lane & 15, bk = kt * 32 + ((lane >> 4) << 3);
      union { u16 h[8]; uint4 q; } pk;
#pragma unroll
      for (int j2 = 0; j2 < 8; j2++) pk.h[j2] = ld[(bk + j2) * 20 + nlo];
      *(uint4*)(dst + (size_t)(kt * 64 + lane) * 8) = pk.q;
    }
    return;
  }
  if (bid >= a.hBase && bid < a.hBase + 256) {
    const int row0 = (bid - a.hBase) * 4;
    if (t < 192) {
      const int rr = t / 48, k = t % 48;
      xs[rr][k] = a.x[(size_t)(row0 + rr) * 48 + k];
    }
    __syncthreads();
    const float bias = a.ginb[t];
    float acc[4] = {bias, bias, bias, bias};
    for (int k = 0; k < 48; k++) {
      const float w = a.ginW[(size_t)k * 256 + t];
#pragma unroll
      for (int rr = 0; rr < 4; rr++) acc[rr] += xs[rr][k] * w;
    }
#pragma unroll
    for (int rr = 0; rr < 4; rr++) a.h_bf[(size_t)(row0 + rr) * 256 + t] = f2b(acc[rr]);
    return;
  }
  if (bid == a.prepBid) {
    a.bkv0[t] = a.mbk[t]; a.bkv0[256 + t] = a.mbv[t];
    a.bqkv1[t] = a.mbq[256 + t]; a.bqkv1[256 + t] = a.mbk[256 + t]; a.bqkv1[512 + t] = a.mbv[256 + t];
    a.bqkv2[t] = a.mbq[512 + t]; a.bqkv2[256 + t] = a.mbk[512 + t]; a.bqkv2[512 + t] = a.mbv[512 + t];
    return;
  }
  if (bid == a.q1Bid) {
    for (int idx = t; idx < 4096; idx += 256) Ss[idx] = a.S[idx];
    __syncthreads();
    float acc[16];
#pragma unroll
    for (int r = 0; r < 16; r++) acc[r] = 0.f;
    for (int k = 0; k < 256; k++) {
      const float w = a.mWq[(size_t)k * 256 + t];
#pragma unroll
      for (int r = 0; r < 16; r++) acc[r] += Ss[r * 256 + k] * w;
    }
    const float bq = a.mbq[t];
#pragma unroll
    for (int r = 0; r < 16; r++) a.q1b[r * 256 + t] = f2b(acc[r] + bq);
    return;
  }
}

// ---------------------------------------------------------------------------
// hWiWj GEMM
// ---------------------------------------------------------------------------
__global__ __launch_bounds__(256) void k_wiwj(
    const u16* __restrict__ h, const u16* __restrict__ frag, float* __restrict__ out) {
  __shared__ __align__(16) u16 As[64 * 264];
  const int t = threadIdx.x, lane = t & 63, wv = t >> 6;
  const int m0 = blockIdx.x * 64, n0 = blockIdx.y * 128;
  {
    const int row = t >> 2, ch = t & 3;
#pragma unroll
    for (int s = 0; s < 8; s++)
      *(uint4*)(As + row * 264 + ch * 64 + s * 8) =
          *(const uint4*)(h + (size_t)(m0 + row) * 256 + ch * 64 + s * 8);
  }
  __syncthreads();
  f4v acc[4][2];
#pragma unroll
  for (int mt = 0; mt < 4; mt++)
#pragma unroll
    for (int nt = 0; nt < 2; nt++) acc[mt][nt] = (f4v){0.f, 0.f, 0.f, 0.f};
  const int Tw = (n0 >> 4) + wv * 2;
#pragma unroll
  for (int kt = 0; kt < 8; kt++) {
    bf8v af[4], bf[2];
#pragma unroll
    for (int mt = 0; mt < 4; mt++)
      af[mt] = *(const bf8v*)(As + (mt * 16 + (lane & 15)) * 264 + kt * 32 + ((lane >> 4) << 3));
#pragma unroll
    for (int nt = 0; nt < 2; nt++)
      bf[nt] = *(const bf8v*)(frag + ((size_t)((Tw + nt) * 8 + kt) * 64 + lane) * 8);
#pragma unroll
    for (int mt = 0; mt < 4; mt++)
#pragma unroll
      for (int nt = 0; nt < 2; nt++)
        acc[mt][nt] = __builtin_amdgcn_mfma_f32_16x16x32_bf16(af[mt], bf[nt], acc[mt][nt], 0, 0, 0);
  }
#pragma unroll
  for (int mt = 0; mt < 4; mt++)
#pragma unroll
    for (int nt = 0; nt < 2; nt++) {
      const int n = n0 + wv * 32 + nt * 16 + (lane & 15);
      const int mb = m0 + mt * 16 + ((lane >> 4) << 2);
#pragma unroll
      for (int r = 0; r < 4; r++) out[(size_t)(mb + r) * 512 + n] = acc[mt][nt][r];
    }
}

// ---------------------------------------------------------------------------
// Edge MLP + masked aggregation (register B-frags, packed bf16 cvt in A-build)
// ---------------------------------------------------------------------------
__global__ __launch_bounds__(256, 2) void k_edge(
    const float* __restrict__ hWiWj, const float* __restrict__ adj,
    const float* __restrict__ geb1, const u16* __restrict__ fragW2,
    const float* __restrict__ geb2, u16* __restrict__ aggB) {
  __shared__ __align__(16) u16 As[64 * 264];
  __shared__ float hi[256];
  __shared__ int jlist[256];
  __shared__ int cnt;
  const int t = threadIdx.x, lane = t & 63, wv = t >> 6;
  const int b = blockIdx.x >> 8, i = blockIdx.x & 255;
  if (t == 0) cnt = 0;
  __syncthreads();
  {
    const float a = adj[(size_t)(b * 256 + i) * 256 + t];
    hi[t] = hWiWj[(size_t)(b * 256 + i) * 512 + t] + geb1[t];
    if (a != 0.f) { const int p = atomicAdd(&cnt, 1); jlist[p] = t; }
  }
  __syncthreads();
  const int nact = cnt;
  if (nact == 0) {
    if (lane < 16) {
#pragma unroll
      for (int nt = 0; nt < 4; nt++)
        aggB[(size_t)(b * 256 + i) * 256 + wv * 64 + nt * 16 + lane] = 0;
    }
    return;
  }
  const int nch = (nact + 63) >> 6;
  float bias2[4];
#pragma unroll
  for (int nt = 0; nt < 4; nt++) bias2[nt] = geb2[wv * 64 + nt * 16 + (lane & 15)];
  float aggAcc[4] = {0.f, 0.f, 0.f, 0.f};
  const u16* fw = fragW2 + lane * 8;

  for (int c = 0; c < nch; c++) {
    const int rows = min(64, nact - c * 64);
    {
      const int r = t >> 2, q = t & 3;
      const bool valid = (r < rows);
      const int j = valid ? jlist[c * 64 + r] : jlist[0];
      const float4* s4 = (const float4*)(hWiWj + (size_t)(b * 256 + j) * 512 + 256 + q * 64);
      u16* dstrow = As + r * 264 + q * 64;
#pragma unroll
      for (int ii = 0; ii < 8; ii++) {
        const float4 v0 = s4[ii * 2];
        const float4 v1 = s4[ii * 2 + 1];
        const int k = q * 64 + ii * 8;
        uint4 qd;
        qd.x = pkbf(fmaxf(v0.x + hi[k + 0], 0.f), fmaxf(v0.y + hi[k + 1], 0.f));
        qd.y = pkbf(fmaxf(v0.z + hi[k + 2], 0.f), fmaxf(v0.w + hi[k + 3], 0.f));
        qd.z = pkbf(fmaxf(v1.x + hi[k + 4], 0.f), fmaxf(v1.y + hi[k + 5], 0.f));
        qd.w = pkbf(fmaxf(v1.z + hi[k + 6], 0.f), fmaxf(v1.w + hi[k + 7], 0.f));
        *(uint4*)(dstrow + ii * 8) = qd;
      }
    }
    __syncthreads();
    f4v acc[4][4];
#pragma unroll
    for (int jt = 0; jt < 4; jt++)
#pragma unroll
      for (int nt = 0; nt < 4; nt++) acc[jt][nt] = (f4v){0.f, 0.f, 0.f, 0.f};
    bf8v bcur[4];
#pragma unroll
    for (int nt = 0; nt < 4; nt++)
      bcur[nt] = *(const bf8v*)(fw + (size_t)((wv * 4 + nt) * 8 + 0) * 512);
#pragma unroll
    for (int kt = 0; kt < 8; kt++) {
      bf8v bnxt[4];
      if (kt < 7) {
#pragma unroll
        for (int nt = 0; nt < 4; nt++)
          bnxt[nt] = *(const bf8v*)(fw + (size_t)((wv * 4 + nt) * 8 + kt + 1) * 512);
      }
      bf8v af[4];
#pragma unroll
      for (int jt = 0; jt < 4; jt++)
        af[jt] = *(const bf8v*)(As + (jt * 16 + (lane & 15)) * 264 + kt * 32 + ((lane >> 4) << 3));
#pragma unroll
      for (int nt = 0; nt < 4; nt++)
#pragma unroll
        for (int jt = 0; jt < 4; jt++)
          acc[jt][nt] = __builtin_amdgcn_mfma_f32_16x16x32_bf16(af[jt], bcur[nt], acc[jt][nt], 0, 0, 0);
      if (kt < 7) {
#pragma unroll
        for (int nt = 0; nt < 4; nt++) bcur[nt] = bnxt[nt];
      }
    }
    const int rbase = (lane >> 4) * 4;
#pragma unroll
    for (int nt = 0; nt < 4; nt++) {
      float s = 0.f;
#pragma unroll
      for (int jt = 0; jt < 4; jt++) {
        const int r0 = jt * 16 + rbase;
#pragma unroll
        for (int r = 0; r < 4; r++) {
          const float e = fmaxf(acc[jt][nt][r] + bias2[nt], 0.f);
          s += (r0 + r < rows) ? e : 0.f;
        }
      }
      s += __shfl_xor(s, 16);
      s += __shfl_xor(s, 32);
      aggAcc[nt] += s;
    }
    __syncthreads();
  }
  if (lane < 16) {
#pragma unroll
    for (int nt = 0; nt < 4; nt++) {
      const int n = wv * 64 + nt * 16 + lane;
      aggB[(size_t)(b * 256 + i) * 256 + n] = f2b(aggAcc[nt]);
    }
  }
}

// ---------------------------------------------------------------------------
// Fused tail, 32 persistent blocks, 9 grid barriers; phase 3 is wave-level.
// ---------------------------------------------------------------------------
#define NBLK 32

__device__ __forceinline__ void gridbar(int* cnt, int gen) {
  __syncthreads();
  if (threadIdx.x == 0) {
    __threadfence();
    __hip_atomic_fetch_add(cnt, 1, __ATOMIC_RELAXED, __HIP_MEMORY_SCOPE_AGENT);
    int it = 0;
    while (__hip_atomic_load(cnt, __ATOMIC_RELAXED, __HIP_MEMORY_SCOPE_AGENT) < NBLK * gen) {
      __builtin_amdgcn_s_sleep(8);
      if (((++it) & 255) == 0)
        __hip_atomic_fetch_add(cnt, 0, __ATOMIC_RELAXED, __HIP_MEMORY_SCOPE_AGENT);
    }
    __threadfence();
  }
  __syncthreads();
}

// M=32 GEMM, A in LDS (stride 264), frag-major B, out LDS bf16 (stride 264)
__device__ void g32(const u16* Al, const u16* frag, const float* bias, int relu,
                    u16* Ol, int t) {
  const int lane = t & 63, wv = t >> 6;
  f4v acc[2][4];
#pragma unroll
  for (int mt = 0; mt < 2; mt++)
#pragma unroll
    for (int nt = 0; nt < 4; nt++) acc[mt][nt] = (f4v){0.f, 0.f, 0.f, 0.f};
#pragma unroll
  for (int kt = 0; kt < 8; kt++) {
    bf8v af[2], bf[4];
#pragma unroll
    for (int mt = 0; mt < 2; mt++)
      af[mt] = *(const bf8v*)(Al + (mt * 16 + (lane & 15)) * 264 + kt * 32 + ((lane >> 4) << 3));
#pragma unroll
    for (int nt = 0; nt < 4; nt++)
      bf[nt] = *(const bf8v*)(frag + ((size_t)((wv * 4 + nt) * 8 + kt) * 64 + lane) * 8);
#pragma unroll
    for (int mt = 0; mt < 2; mt++)
#pragma unroll
      for (int nt = 0; nt < 4; nt++)
        acc[mt][nt] = __builtin_amdgcn_mfma_f32_16x16x32_bf16(af[mt], bf[nt], acc[mt][nt], 0, 0, 0);
  }
#pragma unroll
  for (int mt = 0; mt < 2; mt++)
#pragma unroll
    for (int nt = 0; nt < 4; nt++) {
      const int col = wv * 64 + nt * 16 + (lane & 15);
      const float bv = bias[col];
#pragma unroll
      for (int r = 0; r < 4; r++) {
        const int row = mt * 16 + ((lane >> 4) << 2) + r;
        float v = acc[mt][nt][r] + bv;
        if (relu) v = fmaxf(v, 0.f);
        Ol[row * 264 + col] = f2b(v);
      }
    }
}

// M=32, N=512 GEMM -> global bf16 (kv1)
__device__ void g32kv(const u16* Al, const u16* frag, const float* bias,
                      u16* outG, int t) {
  const int lane = t & 63, wv = t >> 6;
  f4v acc[2][8];
#pragma unroll
  for (int mt = 0; mt < 2; mt++)
#pragma unroll
    for (int nt = 0; nt < 8; nt++) acc[mt][nt] = (f4v){0.f, 0.f, 0.f, 0.f};
#pragma unroll
  for (int kt = 0; kt < 8; kt++) {
    bf8v af[2];
#pragma unroll
    for (int mt = 0; mt < 2; mt++)
      af[mt] = *(const bf8v*)(Al + (mt * 16 + (lane & 15)) * 264 + kt * 32 + ((lane >> 4) << 3));
#pragma unroll
    for (int nt = 0; nt < 8; nt++) {
      const bf8v bf = *(const bf8v*)(frag + ((size_t)((wv * 8 + nt) * 8 + kt) * 64 + lane) * 8);
#pragma unroll
      for (int mt = 0; mt < 2; mt++)
        acc[mt][nt] = __builtin_amdgcn_mfma_f32_16x16x32_bf16(af[mt], bf, acc[mt][nt], 0, 0, 0);
    }
  }
#pragma unroll
  for (int mt = 0; mt < 2; mt++)
#pragma unroll
    for (int nt = 0; nt < 8; nt++) {
      const int col = wv * 128 + nt * 16 + (lane & 15);
      const float bv = bias[col];
#pragma unroll
      for (int r = 0; r < 4; r++) {
        const int row = mt * 16 + ((lane >> 4) << 2) + r;
        outG[(size_t)row * 512 + col] = f2b(acc[mt][nt][r] + bv);
      }
    }
}

// Wave-level M=16 projection unit: one (b, 16-col tile T).
// A: 64x256 bf16 global. mode 1: v = relu(v)+residG. Out bf16 and/or fp32.
__device__ void wproj(const u16* __restrict__ actA, const float* __restrict__ residG,
                      const u16* __restrict__ frag, const float* __restrict__ bias,
                      int mode, u16* __restrict__ outBf, float* __restrict__ outF,
                      int Nout, int b, int T, int lane) {
  f4v acc = (f4v){0.f, 0.f, 0.f, 0.f};
  const u16* abase = actA + (size_t)(b * 16 + (lane & 15)) * 256 + ((lane >> 4) << 3);
  const u16* fbase = frag + ((size_t)(T * 8) * 64 + lane) * 8;
#pragma unroll
  for (int kt = 0; kt < 8; kt++) {
    const bf8v af = *(const bf8v*)(abase + kt * 32);
    const bf8v bf = *(const bf8v*)(fbase + (size_t)kt * 512);
    acc = __builtin_amdgcn_mfma_f32_16x16x32_bf16(af, bf, acc, 0, 0, 0);
  }
  const int col = T * 16 + (lane & 15);
  const float bv = bias[col];
#pragma unroll
  for (int r = 0; r < 4; r++) {
    const int row = b * 16 + ((lane >> 4) << 2) + r;
    float v = acc[r] + bv;
    if (mode == 1) v = fmaxf(v, 0.f) + residG[(size_t)row * 256 + col];
    if (outBf) outBf[(size_t)row * Nout + col] = f2b(v);
    if (outF) outF[(size_t)row * Nout + col] = v;
  }
}

// Wave-level attention unit (Lk=16): one (b,hd). qkvG 64x768 bf16 global.
// O = q + softmax(q k^T/16) v -> attF (fp32) + attB (bf16), 64x256.
__device__ void wattn(const u16* __restrict__ qkvG, float* __restrict__ attF,
                      u16* __restrict__ attB, float* psW, int b, int hd, int lane) {
  const int r = lane & 15, cg = lane >> 4;
  float qv[32];
  {
    const uint4* qp = (const uint4*)(qkvG + (size_t)(b * 16 + r) * 768 + hd * 32);
#pragma unroll
    for (int c4 = 0; c4 < 4; c4++) {
      const uint4 q4 = qp[c4];
      up2(q4.x, qv[c4 * 8 + 0], qv[c4 * 8 + 1]);
      up2(q4.y, qv[c4 * 8 + 2], qv[c4 * 8 + 3]);
      up2(q4.z, qv[c4 * 8 + 4], qv[c4 * 8 + 5]);
      up2(q4.w, qv[c4 * 8 + 6], qv[c4 * 8 + 7]);
    }
  }
  float p[4];
#pragma unroll
  for (int c = 0; c < 4; c++) {
    const int cc = cg * 4 + c;
    const uint4* kp = (const uint4*)(qkvG + (size_t)(b * 16 + cc) * 768 + 256 + hd * 32);
    float s = 0.f;
#pragma unroll
    for (int c4 = 0; c4 < 4; c4++) {
      const uint4 k4 = kp[c4];
      float k0, k1;
      up2(k4.x, k0, k1); s += qv[c4 * 8 + 0] * k0 + qv[c4 * 8 + 1] * k1;
      up2(k4.y, k0, k1); s += qv[c4 * 8 + 2] * k0 + qv[c4 * 8 + 3] * k1;
      up2(k4.z, k0, k1); s += qv[c4 * 8 + 4] * k0 + qv[c4 * 8 + 5] * k1;
      up2(k4.w, k0, k1); s += qv[c4 * 8 + 6] * k0 + qv[c4 * 8 + 7] * k1;
    }
    p[c] = s * 0.0625f;
  }
  float mx = fmaxf(fmaxf(p[0], p[1]), fmaxf(p[2], p[3]));
  mx = fmaxf(mx, __shfl_xor(mx, 16));
  mx = fmaxf(mx, __shfl_xor(mx, 32));
  float sum = 0.f;
#pragma unroll
  for (int c = 0; c < 4; c++) { p[c] = __expf(p[c] - mx); sum += p[c]; }
  sum += __shfl_xor(sum, 16);
  sum += __shfl_xor(sum, 32);
  const float inv = 1.f / sum;
#pragma unroll
  for (int c = 0; c < 4; c++) psW[r * 16 + cg * 4 + c] = p[c] * inv;
  float o[8];
#pragma unroll
  for (int j = 0; j < 8; j++) o[j] = qv[cg * 8 + j];
#pragma unroll
  for (int c = 0; c < 16; c++) {
    const float pv = psW[r * 16 + c];
    const uint4 v4 = *(const uint4*)(qkvG + (size_t)(b * 16 + c) * 768 + 512 + hd * 32 + cg * 8);
    float v0, v1;
    up2(v4.x, v0, v1); o[0] += pv * v0; o[1] += pv * v1;
    up2(v4.y, v0, v1); o[2] += pv * v0; o[3] += pv * v1;
    up2(v4.z, v0, v1); o[4] += pv * v0; o[5] += pv * v1;
    up2(v4.w, v0, v1); o[6] += pv * v0; o[7] += pv * v1;
  }
  const int row = b * 16 + r, col0 = hd * 32 + cg * 8;
#pragma unroll
  for (int j = 0; j < 8; j++) attF[(size_t)row * 256 + col0 + j] = o[j];
  unsigned* ob = (unsigned*)(attB + (size_t)row * 256 + col0);
  ob[0] = pkbf(o[0], o[1]); ob[1] = pkbf(o[2], o[3]);
  ob[2] = pkbf(o[4], o[5]); ob[3] = pkbf(o[6], o[7]);
}

// attn1 (Lk=256), one (b,hd) per block, vectorized loads.
__device__ void attn_tile(const u16* __restrict__ qbuf, int qshared,
                          const u16* __restrict__ kbuf, const u16* __restrict__ vbuf,
                          float* __restrict__ oF, u16* __restrict__ oB,
                          int b, int hd, float* qs, float* sc, float* vs, int t) {
  const int lane = t & 63, wv = t >> 6;
  const int Lk = 256;
  if (t < 64) {
    const int row = t >> 2, part = t & 3;
    const int qrow = qshared ? row : (b * 16 + row);
    const uint4 q4 = *(const uint4*)(qbuf + (size_t)qrow * 256 + hd * 32 + part * 8);
    float f0, f1, f2, f3, f4, f5, f6, f7;
    up2(q4.x, f0, f1); up2(q4.y, f2, f3); up2(q4.z, f4, f5); up2(q4.w, f6, f7);
    float4* d = (float4*)(qs + row * 32 + part * 8);
    d[0] = make_float4(f0, f1, f2, f3);
    d[1] = make_float4(f4, f5, f6, f7);
  }
  __syncthreads();
  {
    float kv[32];
    const uint4* kp = (const uint4*)(kbuf + (size_t)(b * Lk + t) * 512 + hd * 32);
#pragma unroll
    for (int c4 = 0; c4 < 4; c4++) {
      const uint4 k4 = kp[c4];
      up2(k4.x, kv[c4 * 8 + 0], kv[c4 * 8 + 1]);
      up2(k4.y, kv[c4 * 8 + 2], kv[c4 * 8 + 3]);
      up2(k4.z, kv[c4 * 8 + 4], kv[c4 * 8 + 5]);
      up2(k4.w, kv[c4 * 8 + 6], kv[c4 * 8 + 7]);
    }
    for (int r = 0; r < 16; r++) {
      float s = 0.f;
#pragma unroll
      for (int d = 0; d < 32; d++) s += qs[r * 32 + d] * kv[d];
      sc[r * 256 + t] = s * 0.0625f;
    }
  }
  __syncthreads();
  for (int r = wv * 4; r < wv * 4 + 4; r++) {
    float v[4];
    float mx = -1e30f;
#pragma unroll
    for (int q2 = 0; q2 < 4; q2++) {
      v[q2] = sc[r * 256 + lane + q2 * 64];
      mx = fmaxf(mx, v[q2]);
    }
    for (int off = 32; off; off >>= 1) mx = fmaxf(mx, __shfl_xor(mx, off));
    float sum = 0.f;
#pragma unroll
    for (int q2 = 0; q2 < 4; q2++) { v[q2] = __expf(v[q2] - mx); sum += v[q2]; }
    for (int off = 32; off; off >>= 1) sum += __shfl_xor(sum, off);
    const float inv = 1.f / sum;
#pragma unroll
    for (int q2 = 0; q2 < 4; q2++) sc[r * 256 + lane + q2 * 64] = v[q2] * inv;
  }
  __syncthreads();
  for (int u = t; u < 1024; u += 256) {
    const int row = u >> 2, part = u & 3;
    const uint4 v4 = *(const uint4*)(vbuf + (size_t)(b * Lk + row) * 512 + hd * 32 + part * 8);
    float f0, f1, f2, f3, f4, f5, f6, f7;
    up2(v4.x, f0, f1); up2(v4.y, f2, f3); up2(v4.z, f4, f5); up2(v4.w, f6, f7);
    float4* d = (float4*)(vs + row * 32 + part * 8);
    d[0] = make_float4(f0, f1, f2, f3);
    d[1] = make_float4(f4, f5, f6, f7);
  }
  __syncthreads();
  const int r0 = t >> 5, d = t & 31;
  float a0 = qs[r0 * 32 + d], a1 = qs[(r0 + 8) * 32 + d];
#pragma unroll 4
  for (int j = 0; j < Lk; j++) {
    const float vv = vs[j * 32 + d];
    a0 += sc[r0 * 256 + j] * vv;
    a1 += sc[(r0 + 8) * 256 + j] * vv;
  }
  const int c0 = hd * 32 + d;
  oF[(size_t)(b * 16 + r0) * 256 + c0] = a0;
  oB[(size_t)(b * 16 + r0) * 256 + c0] = f2b(a0);
  oF[(size_t)(b * 16 + r0 + 8) * 256 + c0] = a1;
  oB[(size_t)(b * 16 + r0 + 8) * 256 + c0] = f2b(a1);
}

struct TailArgs {
  const u16 *agg, *fGn1, *fGn2, *fGo, *fKV0, *fQKV1, *fQKV2, *fO0, *fO1, *fO2, *fFin, *q1b;
  const float *gnb1, *gnb2, *gob, *bkv0, *bqkv1, *bqkv2, *mbo, *finb;
  u16 *kv1, *o1b, *actBf, *qkvG, *attB;
  float *o1f, *attF, *outF;
  int* bar;
};

__global__ __launch_bounds__(256) void k_tail(TailArgs a) {
  __shared__ __align__(16) char smem[51200];
  const int bid = blockIdx.x, t = threadIdx.x;
  const int lane = t & 63;
  const int wid = bid * 4 + (t >> 6);

  {  // ---- phase 1: rows bid*32..+31: agg -> n1 -> n2 -> enc -> kv1 ----
    u16* actA = (u16*)smem;
    u16* actB = (u16*)(smem + 16896);
    const int r0 = bid * 32;
#pragma unroll
    for (int s = 0; s < 4; s++) {
      const int u = t * 4 + s, row = u >> 5, ch = u & 31;
      *(uint4*)(actA + row * 264 + ch * 8) =
          *(const uint4*)(a.agg + (size_t)(r0 + row) * 256 + ch * 8);
    }
    __syncthreads();
    g32(actA, a.fGn1, a.gnb1, 1, actB, t); __syncthreads();
    g32(actB, a.fGn2, a.gnb2, 1, actA, t); __syncthreads();
    g32(actA, a.fGo, a.gob, 0, actB, t); __syncthreads();
    g32kv(actB, a.fKV0, a.bkv0, a.kv1 + (size_t)r0 * 512, t);
  }
  gridbar(a.bar, 1);
  {  // ---- phase 2: attn1, one (b,hd) per block ----
    float* qs = (float*)smem;
    float* sc = (float*)(smem + 2048);
    float* vs = (float*)(smem + 18432);
    attn_tile(a.q1b, 1, a.kv1, a.kv1 + 256, a.o1f, a.o1b, bid >> 3, bid & 7, qs, sc, vs, t);
  }
  gridbar(a.bar, 2);
  // ---- phase 3: wave-level mab2+mab3+final ----
  float* psW = (float*)smem + (t >> 6) * 256;
  if (wid < 64) wproj(a.o1b, a.o1f, a.fO0, a.mbo, 1, a.actBf, nullptr, 256, wid >> 4, wid & 15, lane);
  gridbar(a.bar, 3);
  for (int u = wid; u < 192; u += 128)
    wproj(a.actBf, nullptr, a.fQKV1, a.bqkv1, 0, a.qkvG, nullptr, 768, u / 48, u % 48, lane);
  gridbar(a.bar, 4);
  if (wid < 32) wattn(a.qkvG, a.attF, a.attB, psW, wid >> 3, wid & 7, lane);
  gridbar(a.bar, 5);
  if (wid < 64) wproj(a.attB, a.attF, a.fO1, a.mbo + 256, 1, a.actBf, nullptr, 256, wid >> 4, wid & 15, lane);
  gridbar(a.bar, 6);
  for (int u = wid; u < 192; u += 128)
    wproj(a.actBf, nullptr, a.fQKV2, a.bqkv2, 0, a.qkvG, nullptr, 768, u / 48, u % 48, lane);
  gridbar(a.bar, 7);
  if (wid < 32) wattn(a.qkvG, a.attF, a.attB, psW, wid >> 3, wid & 7, lane);
  gridbar(a.bar, 8);
  if (wid < 64) wproj(a.attB, a.attF, a.fO2, a.mbo + 512, 1, a.actBf, nullptr, 256, wid >> 4, wid & 15, lane);
  gridbar(a.bar, 9);
  if (wid < 96) wproj(a.actBf, nullptr, a.fFin, a.finb, 0, nullptr, a.outF, 384, wid / 24, wid % 24, lane);
}

// ---------------------------------------------------------------------------
extern "C" void kernel_launch(void* const* d_in, const int* in_sizes, int n_in,
                              void* d_out, int out_size, void* d_ws, size_t ws_size,
                              hipStream_t stream) {
  const float* x    = (const float*)d_in[0];
  const float* adj  = (const float*)d_in[1];
  const float* ginW = (const float*)d_in[2];
  const float* ginb = (const float*)d_in[3];
  const float* geW1 = (const float*)d_in[4];
  const float* geb1 = (const float*)d_in[5];
  const float* geW2 = (const float*)d_in[6];
  const float* geb2 = (const float*)d_in[7];
  const float* gnW1 = (const float*)d_in[8];
  const float* gnb1 = (const float*)d_in[9];
  const float* gnW2 = (const float*)d_in[10];
  const float* gnb2 = (const float*)d_in[11];
  const float* goW  = (const float*)d_in[12];
  const float* gob  = (const float*)d_in[13];
  const float* S    = (const float*)d_in[14];
  const float* mWq  = (const float*)d_in[15];
  const float* mbq  = (const float*)d_in[16];
  const float* mWk  = (const float*)d_in[17];
  const float* mbk  = (const float*)d_in[18];
  const float* mWv  = (const float*)d_in[19];
  const float* mbv  = (const float*)d_in[20];
  const float* mWo  = (const float*)d_in[21];
  const float* mbo  = (const float*)d_in[22];
  const float* finW = (const float*)d_in[23];
  const float* finb = (const float*)d_in[24];
  (void)in_sizes; (void)n_in; (void)out_size; (void)ws_size;

  char* wp = (char*)d_ws;
  size_t off = 0;
  auto alloc = [&](size_t bytes) -> char* {
    char* p = wp + off;
    off += (bytes + 255) & ~(size_t)255;
    return p;
  };
  u16* h_bf     = (u16*)alloc(1024 * 256 * 2);
  float* hWiWjf = (float*)alloc((size_t)1024 * 512 * 4);
  u16* fWiWj    = (u16*)alloc(512 * 256 * 2);
  u16* fW2      = (u16*)alloc(256 * 256 * 2);
  u16* fGn1     = (u16*)alloc(256 * 256 * 2);
  u16* fGn2     = (u16*)alloc(256 * 256 * 2);
  u16* fGo      = (u16*)alloc(256 * 256 * 2);
  u16* fQ0      = (u16*)alloc(256 * 256 * 2);
  u16* fKV0     = (u16*)alloc(512 * 256 * 2);
  u16* fQKV1    = (u16*)alloc(768 * 256 * 2);
  u16* fQKV2    = (u16*)alloc(768 * 256 * 2);
  u16* fO0      = (u16*)alloc(256 * 256 * 2);
  u16* fO1      = (u16*)alloc(256 * 256 * 2);
  u16* fO2      = (u16*)alloc(256 * 256 * 2);
  u16* fFin     = (u16*)alloc(384 * 256 * 2);
  float* bkv0   = (float*)alloc(512 * 4);
  float* bqkv1  = (float*)alloc(768 * 4);
  float* bqkv2  = (float*)alloc(768 * 4);
  u16* q1b      = (u16*)alloc(16 * 256 * 2);
  u16* agg_b    = (u16*)alloc(1024 * 256 * 2);
  u16* kv1      = (u16*)alloc(1024 * 512 * 2);
  float* o1f    = (float*)alloc(64 * 256 * 4);
  u16* o1b      = (u16*)alloc(64 * 256 * 2);
  u16* actBf    = (u16*)alloc(64 * 256 * 2);
  u16* qkvG     = (u16*)alloc(64 * 768 * 2);
  float* attF   = (float*)alloc(64 * 256 * 4);
  u16* attB     = (u16*)alloc(64 * 256 * 2);
  int* bar      = (int*)alloc(256);

  PreArgs P{};
  int nj = 0, tiles = 0;
  auto addF = [&](const float* s, int stride, u16* d, int nT) {
    P.fsrc[nj] = s; P.fdst[nj] = d; P.fstride[nj] = stride; P.fbase[nj] = tiles;
    tiles += nT; nj++;
  };
  addF(geW1, 256, fWiWj, 16);
  addF(geW1 + 65536, 256, fWiWj + 16 * 4096, 16);
  addF(geW2, 256, fW2, 16);
  addF(gnW1, 256, fGn1, 16);
  addF(gnW2, 256, fGn2, 16);
  addF(goW, 256, fGo, 16);
  addF(mWq, 256, fQ0, 16);
  addF(mWk, 256, fKV0, 16);
  addF(mWv, 256, fKV0 + 16 * 4096, 16);
  addF(mWq + 65536, 256, fQKV1, 16);
  addF(mWk + 65536, 256, fQKV1 + 16 * 4096, 16);
  addF(mWv + 65536, 256, fQKV1 + 32 * 4096, 16);
  addF(mWq + 131072, 256, fQKV2, 16);
  addF(mWk + 131072, 256, fQKV2 + 16 * 4096, 16);
  addF(mWv + 131072, 256, fQKV2 + 32 * 4096, 16);
  addF(mWo, 256, fO0, 16);
  addF(mWo + 65536, 256, fO1, 16);
  addF(mWo + 131072, 256, fO2, 16);
  addF(finW, 384, fFin, 24);
  P.fbase[nj] = tiles;
  P.fragTiles = tiles;
  P.hBase = tiles;
  P.prepBid = tiles + 256;
  P.q1Bid = tiles + 257;
  P.x = x; P.ginW = ginW; P.ginb = ginb; P.h_bf = h_bf;
  P.mbk = mbk; P.mbv = mbv; P.mbq = mbq; P.S = S; P.mWq = mWq;
  P.bkv0 = bkv0; P.bqkv1 = bqkv1; P.bqkv2 = bqkv2; P.q1b = q1b;

  TailArgs T{};
  T.agg = agg_b; T.fGn1 = fGn1; T.fGn2 = fGn2; T.fGo = fGo; T.fKV0 = fKV0;
  T.fQKV1 = fQKV1; T.fQKV2 = fQKV2; T.fO0 = fO0; T.fO1 = fO1; T.fO2 = fO2;
  T.fFin = fFin; T.q1b = q1b;
  T.gnb1 = gnb1; T.gnb2 = gnb2; T.gob = gob;
  T.bkv0 = bkv0; T.bqkv1 = bqkv1; T.bqkv2 = bqkv2; T.mbo = mbo; T.finb = finb;
  T.kv1 = kv1; T.o1b = o1b; T.actBf = actBf; T.qkvG = qkvG; T.attB = attB;
  T.o1f = o1f; T.attF = attF; T.outF = (float*)d_out;
  T.bar = bar;

  hipMemsetAsync(bar, 0, 256, stream);
  k_pre<<<dim3(tiles + 258), dim3(256), 0, stream>>>(P);
  k_wiwj<<<dim3(16, 4), dim3(256), 0, stream>>>(h_bf, fWiWj, hWiWjf);
  k_edge<<<dim3(1024), dim3(256), 0, stream>>>(hWiWjf, adj, geb1, fW2, geb2, agg_b);
  k_tail<<<dim3(NBLK), dim3(256), 0, stream>>>(T);
}